// Round 2
// baseline (611.454 us; speedup 1.0000x reference)
//
#include <hip/hip_runtime.h>
#include <stdint.h>

#define NTOK 98
#define DIM 128
#define HEADS 4
#define HD 32
#define BWIN 2048
#define NW 64
#define SCALE 0.17677669529663687f
#define QSTR 40    // qL/kL row stride in u16: 80 B -> 16B-aligned b128 reads, bank-spread
#define VSTR 104   // vL / Pscr row stride in u16: 208 B -> 16B-aligned, bank-spread

typedef __bf16 bf16_t;
typedef bf16_t bf16x8 __attribute__((ext_vector_type(8)));
typedef float f32x4 __attribute__((ext_vector_type(4)));
typedef unsigned short u16;
typedef unsigned int u32;
typedef unsigned long long u64;

__device__ __forceinline__ u16 f2bf(float f) {
    union { float f; u32 u; } v; v.f = f;
    u32 r = v.u + 0x7FFFu + ((v.u >> 16) & 1u);
    return (u16)(r >> 16);
}
__device__ __forceinline__ float bf2f(u16 b) {
    union { u32 u; float f; } v; v.u = ((u32)b) << 16;
    return v.f;
}

// ---------------- K0: prep ----------------------------------------------------
// [0,49152)        qkv_w -> bf16
// [49152,65536)    proj_w -> bf16
// [65536,2524160)  mb[w][h][i*98+j] = bf16(mask[w][ij] + bias_table[rel_idx[ij]][h])
__global__ void k0_prep(const float* __restrict__ qkv_w, const float* __restrict__ proj_w,
                        const float* __restrict__ mask,
                        const float* __restrict__ bias_table, const int* __restrict__ rel_idx,
                        u16* __restrict__ qkvw_bf, u16* __restrict__ pw_bf,
                        u16* __restrict__ mb)
{
    int t = blockIdx.x * 256 + threadIdx.x;
    if (t < 49152) {
        qkvw_bf[t] = f2bf(qkv_w[t]);
    } else if (t < 65536) {
        int r = t - 49152;
        pw_bf[r] = f2bf(proj_w[r]);
    } else if (t < 2524160) {
        int r = t - 65536;                 // [0, 64*4*9604)
        int w   = r / (HEADS * 9604);
        int rem = r - w * (HEADS * 9604);
        int hh  = rem / 9604;
        int ij  = rem - hh * 9604;
        mb[r] = f2bf(mask[w * 9604 + ij] + bias_table[rel_idx[ij] * HEADS + hh]);
    }
}

// ---------------- fused: qkv GEMM -> attention -> proj, all per-window --------
// LDS (142624 B, 1 block/CU, 8 waves = 2/SIMD):
//   XO   [98][136] u16 : x (bf16) during phase 2; O during phases 3/4 (aliased)
//   qLs  [4][98][40]   : q per head, pre-scaled
//   kLs  [4][98][40]   : k per head
//   vLs  [4][32][104]  : v^T per head (d-major, B-frag layout for PV)
//   Pscr [8][16][104]  : per-wave P transpose scratch
__global__ __launch_bounds__(512) void k_fused(
    const float* __restrict__ x, const u16* __restrict__ qkvw_bf,
    const float* __restrict__ qkv_b, const u16* __restrict__ mb,
    const u16* __restrict__ pw_bf, const float* __restrict__ proj_b,
    float* __restrict__ out)
{
    __shared__ __align__(16) u16 XO[98 * 136];
    __shared__ __align__(16) u16 qLs[HEADS][98 * QSTR];
    __shared__ __align__(16) u16 kLs[HEADS][98 * QSTR];
    __shared__ __align__(16) u16 vLs[HEADS][HD * VSTR];
    __shared__ __align__(16) u16 Pscr[8][16 * VSTR];

    const int b    = blockIdx.x;
    const int tid  = threadIdx.x;
    const int wave = tid >> 6;
    const int lane = tid & 63;
    const int l16  = lane & 15;
    const int quad = lane >> 4;

    // ---- phase 1: stage x[b] -> bf16 LDS ------------------------------------
    const float* xb = x + (size_t)b * (NTOK * DIM);
    for (int idx = tid; idx < (NTOK * DIM / 4); idx += 512) {
        int row = idx >> 5;
        int c4  = idx & 31;
        const float4 v = reinterpret_cast<const float4*>(xb)[idx];
        u64 pack = (u64)f2bf(v.x) | ((u64)f2bf(v.y) << 16) |
                   ((u64)f2bf(v.z) << 32) | ((u64)f2bf(v.w) << 48);
        *reinterpret_cast<u64*>(&XO[row * 136 + c4 * 4]) = pack;
    }
    __syncthreads();

    // ---- phase 2: qkv GEMM, outputs to LDS ----------------------------------
    // 21 (part, mt) units round-robin over 8 waves; full N=128 per unit
    for (int u = wave; u < 21; u += 8) {
        int part = u / 7;
        int mt   = u % 7;
        int arow = mt * 16 + l16;
        if (arow > 97) arow = 97;          // pad rows duplicate row 97 (discarded)
        bf16x8 af[4];
#pragma unroll
        for (int ks = 0; ks < 4; ++ks)
            af[ks] = *reinterpret_cast<const bf16x8*>(&XO[arow * 136 + quad * 8 + ks * 32]);
        const int tokb = mt * 16 + quad * 4;
        const u16* wp = qkvw_bf + (size_t)part * DIM * DIM;

#pragma unroll
        for (int np = 0; np < 4; ++np) {   // nt pairs: (2np, 2np+1)
            f32x4 acc0 = {0.f, 0.f, 0.f, 0.f};
            f32x4 acc1 = {0.f, 0.f, 0.f, 0.f};
#pragma unroll
            for (int ks = 0; ks < 4; ++ks) {
                bf16x8 b0 = *reinterpret_cast<const bf16x8*>(
                    wp + ((np * 2 + 0) * 16 + l16) * DIM + quad * 8 + ks * 32);
                bf16x8 b1 = *reinterpret_cast<const bf16x8*>(
                    wp + ((np * 2 + 1) * 16 + l16) * DIM + quad * 8 + ks * 32);
                acc0 = __builtin_amdgcn_mfma_f32_16x16x32_bf16(af[ks], b0, acc0, 0, 0, 0);
                acc1 = __builtin_amdgcn_mfma_f32_16x16x32_bf16(af[ks], b1, acc1, 0, 0, 0);
            }
#pragma unroll
            for (int half = 0; half < 2; ++half) {
                const f32x4& acc = half ? acc1 : acc0;
                int col = (np * 2 + half) * 16 + l16;     // 0..127
                int h   = col >> 5;
                int d   = col & 31;
                float cb = qkv_b[part * DIM + col];
                if (part == 0) {
#pragma unroll
                    for (int reg = 0; reg < 4; ++reg) {
                        int tok = tokb + reg;
                        if (tok < NTOK)
                            qLs[h][tok * QSTR + d] = f2bf((acc[reg] + cb) * SCALE);
                    }
                } else if (part == 1) {
#pragma unroll
                    for (int reg = 0; reg < 4; ++reg) {
                        int tok = tokb + reg;
                        if (tok < NTOK)
                            kLs[h][tok * QSTR + d] = f2bf(acc[reg] + cb);
                    }
                } else {
                    u16* vrow = &vLs[h][d * VSTR];
                    if (tokb + 3 <= 97) {
                        u64 pack = 0;
#pragma unroll
                        for (int reg = 0; reg < 4; ++reg)
                            pack |= ((u64)f2bf(acc[reg] + cb)) << (16 * reg);
                        *reinterpret_cast<u64*>(&vrow[tokb]) = pack;
                    } else if (tokb <= 97) {   // tokb == 96: tokens 96,97
                        u32 pack = (u32)f2bf(acc[0] + cb) | ((u32)f2bf(acc[1] + cb) << 16);
                        *reinterpret_cast<u32*>(&vrow[tokb]) = pack;
                    }
                }
            }
        }
    }
    __syncthreads();   // qkv complete; XO (x) is dead from here -> reuse as Obuf

    // ---- phase 3: attention; 2 waves per head (mt-split), barrier-free ------
    {
        const int h   = wave >> 1;
        const int mlo = (wave & 1) ? 4 : 0;
        const int mhi = (wave & 1) ? 7 : 4;
        const u16* qh  = &qLs[h][0];
        const u16* kh  = &kLs[h][0];
        const u16* vh  = &vLs[h][0];
        const u16* mbp = mb + ((size_t)((b & (NW - 1)) * HEADS + h)) * 9604;
        u16* ps = &Pscr[wave][0];

        bf16x8 kf[7];
#pragma unroll
        for (int nj = 0; nj < 7; ++nj)
            kf[nj] = *reinterpret_cast<const bf16x8*>(&kh[(nj * 16 + l16) * QSTR + quad * 8]);

        for (int mt = mlo; mt < mhi; ++mt) {
            bf16x8 qf = *reinterpret_cast<const bf16x8*>(&qh[(mt * 16 + l16) * QSTR + quad * 8]);
            f32x4 sacc[7];
#pragma unroll
            for (int nj = 0; nj < 7; ++nj) {
                f32x4 z = {0.f, 0.f, 0.f, 0.f};
                sacc[nj] = __builtin_amdgcn_mfma_f32_16x16x32_bf16(qf, kf[nj], z, 0, 0, 0);
            }
#pragma unroll
            for (int reg = 0; reg < 4; ++reg) {
                int i = mt * 16 + quad * 4 + reg;
                bool irow = (i < NTOK);
                float s[7];
#pragma unroll
                for (int nj = 0; nj < 7; ++nj) {
                    int j = nj * 16 + l16;
                    float val = -1e30f;
                    if (irow && j < NTOK)
                        val = sacc[nj][reg] + bf2f(mbp[i * NTOK + j]);
                    s[nj] = val;
                }
                float mx = s[0];
#pragma unroll
                for (int nj = 1; nj < 7; ++nj) mx = fmaxf(mx, s[nj]);
#pragma unroll
                for (int off = 1; off < 16; off <<= 1) mx = fmaxf(mx, __shfl_xor(mx, off));
                float p[7];
                float lsum = 0.f;
#pragma unroll
                for (int nj = 0; nj < 7; ++nj) {
                    float pv = (s[nj] > -1e29f) ? __expf(s[nj] - mx) : 0.f;
                    p[nj] = pv;
                    lsum += pv;
                }
#pragma unroll
                for (int off = 1; off < 16; off <<= 1) lsum += __shfl_xor(lsum, off);
                float rinv = 1.f / ((lsum > 0.f) ? lsum : 1.f);
#pragma unroll
                for (int nj = 0; nj < 7; ++nj) {
                    int j = nj * 16 + l16;
                    if (irow && j < NTOK)
                        ps[(quad * 4 + reg) * VSTR + j] = f2bf(p[nj] * rinv);
                }
            }
            // P (C-layout) -> A-frags via wave-private scratch (no barrier needed)
            bf16x8 pf[3];
#pragma unroll
            for (int ks = 0; ks < 3; ++ks)
                pf[ks] = *reinterpret_cast<const bf16x8*>(&ps[l16 * VSTR + quad * 8 + ks * 32]);
#pragma unroll
            for (int nt = 0; nt < 2; ++nt) {
                f32x4 oacc = {0.f, 0.f, 0.f, 0.f};
#pragma unroll
                for (int ks = 0; ks < 3; ++ks) {
                    bf16x8 vf = *reinterpret_cast<const bf16x8*>(
                        &vh[(nt * 16 + l16) * VSTR + quad * 8 + ks * 32]);
                    oacc = __builtin_amdgcn_mfma_f32_16x16x32_bf16(pf[ks], vf, oacc, 0, 0, 0);
                }
                int d = nt * 16 + l16;
                float v96 = bf2f(vh[d * VSTR + 96]);
                float v97 = bf2f(vh[d * VSTR + 97]);
#pragma unroll
                for (int reg = 0; reg < 4; ++reg) {
                    int i = mt * 16 + quad * 4 + reg;
                    if (i < NTOK) {
                        float p96 = bf2f(ps[(quad * 4 + reg) * VSTR + 96]);
                        float p97 = bf2f(ps[(quad * 4 + reg) * VSTR + 97]);
                        XO[i * 136 + h * HD + d] = f2bf(oacc[reg] + p96 * v96 + p97 * v97);
                    }
                }
            }
        }
    }
    __syncthreads();

    // ---- phase 4: proj: out[b] = O @ proj_w^T + proj_b ----------------------
    for (int t = wave; t < 56; t += 8) {
        int mt = t >> 3;
        int nt = t & 7;
        int arow = mt * 16 + l16;
        if (arow > 97) arow = 97;
        bf16x8 af[4];
#pragma unroll
        for (int ks = 0; ks < 4; ++ks)
            af[ks] = *reinterpret_cast<const bf16x8*>(&XO[arow * 136 + quad * 8 + ks * 32]);
        f32x4 acc = {0.f, 0.f, 0.f, 0.f};
#pragma unroll
        for (int ks = 0; ks < 4; ++ks) {
            bf16x8 bw = *reinterpret_cast<const bf16x8*>(
                pw_bf + (nt * 16 + l16) * DIM + quad * 8 + ks * 32);
            acc = __builtin_amdgcn_mfma_f32_16x16x32_bf16(af[ks], bw, acc, 0, 0, 0);
        }
        int col = nt * 16 + l16;
        float pb = proj_b[col];
#pragma unroll
        for (int reg = 0; reg < 4; ++reg) {
            int row = mt * 16 + quad * 4 + reg;
            if (row < NTOK)
                out[((size_t)b * NTOK + row) * DIM + col] = acc[reg] + pb;
        }
    }
}

// ---------------- launch ------------------------------------------------------
extern "C" void kernel_launch(void* const* d_in, const int* in_sizes, int n_in,
                              void* d_out, int out_size, void* d_ws, size_t ws_size,
                              hipStream_t stream)
{
    const float* x       = (const float*)d_in[0];
    const float* mask    = (const float*)d_in[1];
    const float* qkv_w   = (const float*)d_in[2];
    const float* qkv_b   = (const float*)d_in[3];
    const float* proj_w  = (const float*)d_in[4];
    const float* proj_b  = (const float*)d_in[5];
    const float* bias_tb = (const float*)d_in[6];
    const int*   rel_idx = (const int*)d_in[7];
    float* out = (float*)d_out;

    char* ws = (char*)d_ws;
    u16* qkvw_bf = (u16*)(ws + 0);          //    98304 B
    u16* pw_bf   = (u16*)(ws + 98304);      //    32768 B
    u16* mb      = (u16*)(ws + 131072);     //  4917248 B (64*4*9604 u16)
    // total ~5.0 MB (q/k/v global round-trip eliminated)

    k0_prep<<<9861, 256, 0, stream>>>(qkv_w, proj_w, mask, bias_tb, rel_idx,
                                      qkvw_bf, pw_bf, mb);
    k_fused<<<BWIN, 512, 0, stream>>>(x, qkvw_bf, qkv_b, mb, pw_bf, proj_b, out);
}

// Round 3
// 403.910 us; speedup vs baseline: 1.5138x; 1.5138x over previous
//
#include <hip/hip_runtime.h>
#include <stdint.h>

#define NTOK 98
#define DIM 128
#define HEADS 4
#define HD 32
#define BWIN 2048
#define NW 64
#define SCALE 0.17677669529663687f
#define QSTR 40    // qL/kL row stride in u16: 80 B -> 16B-aligned b128 reads, bank-spread
#define VSTR 104   // vL / Pscr row stride in u16: 208 B -> 16B-aligned, bank-spread

typedef __bf16 bf16_t;
typedef bf16_t bf16x8 __attribute__((ext_vector_type(8)));
typedef float f32x4 __attribute__((ext_vector_type(4)));
typedef unsigned short u16;
typedef unsigned int u32;
typedef unsigned long long u64;

__device__ __forceinline__ u16 f2bf(float f) {
    union { bf16_t h; u16 u; } v; v.h = (bf16_t)f; return v.u;
}
__device__ __forceinline__ float bf2f(u16 b) {
    union { u16 u; bf16_t h; } v; v.u = b; return (float)v.h;
}

// ---------------- K0: prep ----------------------------------------------------
// [0,49152)          qkv_w -> bf16
// [49152,65536)      proj_w -> bf16
// [65536,3276800)    mbT[w][h][i][l16][njp] = bf16(mask[w][i][j] + bias[rel_idx[i][j]][h])
//                    where j = njp*16 + l16, njp in [0,8) (njp==7 and j>=98 -> 0)
//                    -> phase-3 lane reads its 7 bias values as ONE b128 load
__global__ void k0_prep(const float* __restrict__ qkv_w, const float* __restrict__ proj_w,
                        const float* __restrict__ mask,
                        const float* __restrict__ bias_table, const int* __restrict__ rel_idx,
                        u16* __restrict__ qkvw_bf, u16* __restrict__ pw_bf,
                        u16* __restrict__ mbT)
{
    int t = blockIdx.x * 256 + threadIdx.x;
    if (t < 49152) {
        qkvw_bf[t] = f2bf(qkv_w[t]);
    } else if (t < 65536) {
        int r = t - 49152;
        pw_bf[r] = f2bf(proj_w[r]);
    } else {
        int r = t - 65536;                  // [0, 64*4*98*128)
        int w    = r / 50176;               // 4*98*128
        int rem  = r - w * 50176;
        int hh   = rem / 12544;             // 98*128
        int rem2 = rem - hh * 12544;
        int i    = rem2 >> 7;
        int c    = rem2 & 127;
        int l16  = c >> 3;
        int njp  = c & 7;
        int j    = njp * 16 + l16;
        float val = 0.f;
        if (njp < 7 && j < NTOK)
            val = mask[w * 9604 + i * NTOK + j] + bias_table[rel_idx[i * NTOK + j] * HEADS + hh];
        mbT[r] = f2bf(val);
    }
}

// ---------------- fused: qkv GEMM -> attention -> proj, all per-window --------
// LDS (144672 B, 1 block/CU, 8 waves = 2/SIMD):
//   XO    [98][136] u16 : x (bf16) during phase 2; O during phases 3/4 (aliased)
//   qLs   [4][98][40]   : q per head, pre-scaled
//   kLs   [4][98][40]   : k per head
//   vLs   [4][32][104]  : v^T per head (d-major, B-frag layout for PV)
//   Pscr  [8][16][104]  : per-wave P transpose scratch
//   qkvb_l/projb_l      : biases
__global__ __launch_bounds__(512, 2) void k_fused(
    const float* __restrict__ x, const u16* __restrict__ qkvw_bf,
    const float* __restrict__ qkv_b, const u16* __restrict__ mbT,
    const u16* __restrict__ pw_bf, const float* __restrict__ proj_b,
    float* __restrict__ out)
{
    __shared__ __align__(16) u16 XO[98 * 136];
    __shared__ __align__(16) u16 qLs[HEADS][98 * QSTR];
    __shared__ __align__(16) u16 kLs[HEADS][98 * QSTR];
    __shared__ __align__(16) u16 vLs[HEADS][HD * VSTR];
    __shared__ __align__(16) u16 Pscr[8][16 * VSTR];
    __shared__ float qkvb_l[384];
    __shared__ float projb_l[128];

    const int b    = blockIdx.x;
    const int tid  = threadIdx.x;
    const int wave = tid >> 6;
    const int lane = tid & 63;
    const int l16  = lane & 15;
    const int quad = lane >> 4;

    // ---- phase 1: stage x[b] -> bf16 LDS; biases -> LDS ---------------------
    if (tid < 384) qkvb_l[tid] = qkv_b[tid];
    else projb_l[tid - 384] = proj_b[tid - 384];

    const float* xb = x + (size_t)b * (NTOK * DIM);
    for (int idx = tid; idx < (NTOK * DIM / 4); idx += 512) {
        int row = idx >> 5;
        int c4  = idx & 31;
        const float4 v = reinterpret_cast<const float4*>(xb)[idx];
        u64 pack = (u64)f2bf(v.x) | ((u64)f2bf(v.y) << 16) |
                   ((u64)f2bf(v.z) << 32) | ((u64)f2bf(v.w) << 48);
        *reinterpret_cast<u64*>(&XO[row * 136 + c4 * 4]) = pack;
    }
    __syncthreads();

    // ---- phase 2: qkv GEMM, outputs to LDS ----------------------------------
    // part-major contiguous chunks: waves 0-4 get 3 units, 5-7 get 2 units.
    // np-outer so the 8 B-fragments (weights, global) are register-cached
    // across all mt units of the same part.
    {
        const int u0 = wave * 3 - ((wave > 5) ? (wave - 5) : 0);
        const int u1 = u0 + ((wave < 5) ? 3 : 2);
        for (int np = 0; np < 4; ++np) {
            int cached = -1;
            bf16x8 Bf[2][4];
            for (int u = u0; u < u1; ++u) {
                const int part = u / 7;
                const int mt   = u - part * 7;
                if (part != cached) {
                    const u16* wp = qkvw_bf + (size_t)part * DIM * DIM;
#pragma unroll
                    for (int half = 0; half < 2; ++half)
#pragma unroll
                        for (int ks = 0; ks < 4; ++ks)
                            Bf[half][ks] = *reinterpret_cast<const bf16x8*>(
                                wp + ((np * 2 + half) * 16 + l16) * DIM + quad * 8 + ks * 32);
                    cached = part;
                }
                int arow = mt * 16 + l16;
                if (arow > 97) arow = 97;      // pad rows duplicate row 97 (discarded)
                f32x4 acc0 = {0.f, 0.f, 0.f, 0.f};
                f32x4 acc1 = {0.f, 0.f, 0.f, 0.f};
#pragma unroll
                for (int ks = 0; ks < 4; ++ks) {
                    bf16x8 a = *reinterpret_cast<const bf16x8*>(
                        &XO[arow * 136 + quad * 8 + ks * 32]);
                    acc0 = __builtin_amdgcn_mfma_f32_16x16x32_bf16(a, Bf[0][ks], acc0, 0, 0, 0);
                    acc1 = __builtin_amdgcn_mfma_f32_16x16x32_bf16(a, Bf[1][ks], acc1, 0, 0, 0);
                }
                const int tokb = mt * 16 + quad * 4;
#pragma unroll
                for (int half = 0; half < 2; ++half) {
                    const f32x4& acc = half ? acc1 : acc0;
                    int col = (np * 2 + half) * 16 + l16;     // 0..127
                    int h   = col >> 5;
                    int d   = col & 31;
                    float cb = qkvb_l[part * DIM + col];
                    if (part == 0) {
#pragma unroll
                        for (int reg = 0; reg < 4; ++reg) {
                            int tok = tokb + reg;
                            if (tok < NTOK)
                                qLs[h][tok * QSTR + d] = f2bf((acc[reg] + cb) * SCALE);
                        }
                    } else if (part == 1) {
#pragma unroll
                        for (int reg = 0; reg < 4; ++reg) {
                            int tok = tokb + reg;
                            if (tok < NTOK)
                                kLs[h][tok * QSTR + d] = f2bf(acc[reg] + cb);
                        }
                    } else {
                        u16* vrow = &vLs[h][d * VSTR];
                        if (tokb + 3 <= 97) {
                            u64 pack = 0;
#pragma unroll
                            for (int reg = 0; reg < 4; ++reg)
                                pack |= ((u64)f2bf(acc[reg] + cb)) << (16 * reg);
                            *reinterpret_cast<u64*>(&vrow[tokb]) = pack;
                        } else if (tokb <= 97) {   // tokb == 96: tokens 96,97
                            u32 pack = (u32)f2bf(acc[0] + cb) | ((u32)f2bf(acc[1] + cb) << 16);
                            *reinterpret_cast<u32*>(&vrow[tokb]) = pack;
                        }
                    }
                }
            }
        }
    }
    __syncthreads();   // qkv complete; XO (x) is dead from here -> reuse as Obuf

    // ---- phase 3: attention; 2 waves per head (mt-split), barrier-free ------
    {
        const int h   = wave >> 1;
        const int mlo = (wave & 1) ? 4 : 0;
        const int mhi = (wave & 1) ? 7 : 4;
        const u16* qh  = &qLs[h][0];
        const u16* kh  = &kLs[h][0];
        const u16* vh  = &vLs[h][0];
        const u16* mbtp = mbT + ((size_t)((b & (NW - 1)) * HEADS + h)) * (NTOK * 128);
        u16* ps = &Pscr[wave][0];

        bf16x8 kf[7];
#pragma unroll
        for (int nj = 0; nj < 7; ++nj)
            kf[nj] = *reinterpret_cast<const bf16x8*>(&kh[(nj * 16 + l16) * QSTR + quad * 8]);

        for (int mt = mlo; mt < mhi; ++mt) {
            // issue mask+bias vector loads first so they overlap the MFMAs
            bf16x8 mrows[4];
#pragma unroll
            for (int reg = 0; reg < 4; ++reg) {
                int i  = mt * 16 + quad * 4 + reg;
                int ic = (i > 97) ? 97 : i;
                mrows[reg] = *reinterpret_cast<const bf16x8*>(&mbtp[ic * 128 + l16 * 8]);
            }
            bf16x8 qf = *reinterpret_cast<const bf16x8*>(&qh[(mt * 16 + l16) * QSTR + quad * 8]);
            f32x4 sacc[7];
#pragma unroll
            for (int nj = 0; nj < 7; ++nj) {
                f32x4 z = {0.f, 0.f, 0.f, 0.f};
                sacc[nj] = __builtin_amdgcn_mfma_f32_16x16x32_bf16(qf, kf[nj], z, 0, 0, 0);
            }
#pragma unroll
            for (int reg = 0; reg < 4; ++reg) {
                int i = mt * 16 + quad * 4 + reg;
                bool irow = (i < NTOK);
                float s[7];
#pragma unroll
                for (int nj = 0; nj < 7; ++nj) {
                    int j = nj * 16 + l16;
                    float val = -1e30f;
                    if (irow && j < NTOK)
                        val = sacc[nj][reg] + (float)mrows[reg][nj];
                    s[nj] = val;
                }
                float mx = s[0];
#pragma unroll
                for (int nj = 1; nj < 7; ++nj) mx = fmaxf(mx, s[nj]);
#pragma unroll
                for (int off = 1; off < 16; off <<= 1) mx = fmaxf(mx, __shfl_xor(mx, off));
                float p[7];
                float lsum = 0.f;
#pragma unroll
                for (int nj = 0; nj < 7; ++nj) {
                    float pv = (s[nj] > -1e29f) ? __expf(s[nj] - mx) : 0.f;
                    p[nj] = pv;
                    lsum += pv;
                }
#pragma unroll
                for (int off = 1; off < 16; off <<= 1) lsum += __shfl_xor(lsum, off);
                float rinv = 1.f / ((lsum > 0.f) ? lsum : 1.f);
#pragma unroll
                for (int nj = 0; nj < 7; ++nj) {
                    int j = nj * 16 + l16;
                    if (irow && j < NTOK)
                        ps[(quad * 4 + reg) * VSTR + j] = f2bf(p[nj] * rinv);
                }
            }
            // P (C-layout) -> A-frags via wave-private scratch (no barrier needed)
            bf16x8 pf[3];
#pragma unroll
            for (int ks = 0; ks < 3; ++ks)
                pf[ks] = *reinterpret_cast<const bf16x8*>(&ps[l16 * VSTR + quad * 8 + ks * 32]);
#pragma unroll
            for (int nt = 0; nt < 2; ++nt) {
                f32x4 oacc = {0.f, 0.f, 0.f, 0.f};
#pragma unroll
                for (int ks = 0; ks < 3; ++ks) {
                    bf16x8 vf = *reinterpret_cast<const bf16x8*>(
                        &vh[(nt * 16 + l16) * VSTR + quad * 8 + ks * 32]);
                    oacc = __builtin_amdgcn_mfma_f32_16x16x32_bf16(pf[ks], vf, oacc, 0, 0, 0);
                }
                int d = nt * 16 + l16;
                float v96 = bf2f(vh[d * VSTR + 96]);
                float v97 = bf2f(vh[d * VSTR + 97]);
#pragma unroll
                for (int reg = 0; reg < 4; ++reg) {
                    int i = mt * 16 + quad * 4 + reg;
                    if (i < NTOK) {
                        float p96 = bf2f(ps[(quad * 4 + reg) * VSTR + 96]);
                        float p97 = bf2f(ps[(quad * 4 + reg) * VSTR + 97]);
                        XO[i * 136 + h * HD + d] = f2bf(oacc[reg] + p96 * v96 + p97 * v97);
                    }
                }
            }
        }
    }
    __syncthreads();

    // ---- phase 4: proj: out[b] = O @ proj_w^T + proj_b ----------------------
    // nt == wave is constant per wave -> B-fragments loaded once, reused 7x
    {
        const int nt = wave;
        bf16x8 bw[4];
#pragma unroll
        for (int ks = 0; ks < 4; ++ks)
            bw[ks] = *reinterpret_cast<const bf16x8*>(
                pw_bf + (nt * 16 + l16) * DIM + quad * 8 + ks * 32);
        const int col = nt * 16 + l16;
        const float pb = projb_l[col];
        for (int mt = 0; mt < 7; ++mt) {
            int arow = mt * 16 + l16;
            if (arow > 97) arow = 97;
            f32x4 acc = {0.f, 0.f, 0.f, 0.f};
#pragma unroll
            for (int ks = 0; ks < 4; ++ks) {
                bf16x8 a = *reinterpret_cast<const bf16x8*>(
                    &XO[arow * 136 + quad * 8 + ks * 32]);
                acc = __builtin_amdgcn_mfma_f32_16x16x32_bf16(a, bw[ks], acc, 0, 0, 0);
            }
#pragma unroll
            for (int reg = 0; reg < 4; ++reg) {
                int row = mt * 16 + quad * 4 + reg;
                if (row < NTOK)
                    out[((size_t)b * NTOK + row) * DIM + col] = acc[reg] + pb;
            }
        }
    }
}

// ---------------- launch ------------------------------------------------------
extern "C" void kernel_launch(void* const* d_in, const int* in_sizes, int n_in,
                              void* d_out, int out_size, void* d_ws, size_t ws_size,
                              hipStream_t stream)
{
    const float* x       = (const float*)d_in[0];
    const float* mask    = (const float*)d_in[1];
    const float* qkv_w   = (const float*)d_in[2];
    const float* qkv_b   = (const float*)d_in[3];
    const float* proj_w  = (const float*)d_in[4];
    const float* proj_b  = (const float*)d_in[5];
    const float* bias_tb = (const float*)d_in[6];
    const int*   rel_idx = (const int*)d_in[7];
    float* out = (float*)d_out;

    char* ws = (char*)d_ws;
    u16* qkvw_bf = (u16*)(ws + 0);          //    98304 B
    u16* pw_bf   = (u16*)(ws + 98304);      //    32768 B
    u16* mbT     = (u16*)(ws + 131072);     //  6422528 B (64*4*98*128 u16, transposed-tiled)
    // total ~6.25 MB

    k0_prep<<<12800, 256, 0, stream>>>(qkv_w, proj_w, mask, bias_tb, rel_idx,
                                       qkvw_bf, pw_bf, mbT);
    k_fused<<<BWIN, 512, 0, stream>>>(x, qkvw_bf, qkv_b, mbT, pw_bf, proj_b, out);
}

// Round 4
// 389.383 us; speedup vs baseline: 1.5703x; 1.0373x over previous
//
#include <hip/hip_runtime.h>
#include <stdint.h>

#define NTOK 98
#define DIM 128
#define HEADS 4
#define HD 32
#define BWIN 2048
#define NW 64
#define SCALE 0.17677669529663687f
#define QSTR 40    // qL/kL row stride in u16: 80 B -> 16B-aligned b128 reads, 2-way banks (free)
#define VSTR 104   // vL / Pscr row stride in u16: 208 B -> 16B-aligned, 2-way banks (free)

typedef __bf16 bf16_t;
typedef bf16_t bf16x8 __attribute__((ext_vector_type(8)));
typedef float f32x4 __attribute__((ext_vector_type(4)));
typedef unsigned short u16;
typedef unsigned int u32;
typedef unsigned long long u64;

__device__ __forceinline__ u16 f2bf(float f) {
    union { bf16_t h; u16 u; } v; v.h = (bf16_t)f; return v.u;
}
__device__ __forceinline__ float bf2f(u16 b) {
    union { u16 u; bf16_t h; } v; v.u = b; return (float)v.h;
}

// ---------------- K0: prep ----------------------------------------------------
// [0,49152)          qkv_w -> bf16
// [49152,65536)      proj_w -> bf16
// [65536,3276800)    mbT[w][h][i][l16][njp] = bf16(mask[w][i][j] + bias[rel_idx[i][j]][h])
//                    j = njp*16 + l16, njp in [0,8) (njp==7 or j>=98 -> 0)
//                    -> attention lane reads its 7 mask+bias values as ONE b128 load
__global__ void k0_prep(const float* __restrict__ qkv_w, const float* __restrict__ proj_w,
                        const float* __restrict__ mask,
                        const float* __restrict__ bias_table, const int* __restrict__ rel_idx,
                        u16* __restrict__ qkvw_bf, u16* __restrict__ pw_bf,
                        u16* __restrict__ mbT)
{
    int t = blockIdx.x * 256 + threadIdx.x;
    if (t < 49152) {
        qkvw_bf[t] = f2bf(qkv_w[t]);
    } else if (t < 65536) {
        int r = t - 49152;
        pw_bf[r] = f2bf(proj_w[r]);
    } else {
        int r = t - 65536;                  // [0, 64*4*98*128)
        int w    = r / 50176;               // 4*98*128
        int rem  = r - w * 50176;
        int hh   = rem / 12544;             // 98*128
        int rem2 = rem - hh * 12544;
        int i    = rem2 >> 7;
        int c    = rem2 & 127;
        int l16  = c >> 3;
        int njp  = c & 7;
        int j    = njp * 16 + l16;
        float val = 0.f;
        if (njp < 7 && j < NTOK)
            val = mask[w * 9604 + i * NTOK + j] + bias_table[rel_idx[i * NTOK + j] * HEADS + hh];
        mbT[r] = f2bf(val);
    }
}

// ---------------- K1: qkv GEMM + attention, block = (window, head) -----------
// 256 threads (4 waves), LDS 35648 B -> 4 blocks/CU (16 waves/CU).
// Phase A: qkv GEMM for this head's 32 cols x 3 parts; A-frags built directly
//          from global x (f32->bf16), B-frags register-cached per part.
// Phase B: attention (verified body), O -> global bf16 OG[b][i][h*32+d].
__global__ __launch_bounds__(256, 4) void k_attn(
    const float* __restrict__ x, const u16* __restrict__ qkvw_bf,
    const float* __restrict__ qkv_b, const u16* __restrict__ mbT,
    u16* __restrict__ OG)
{
    __shared__ __align__(16) u16 qL[NTOK * QSTR];     //  7840 B
    __shared__ __align__(16) u16 kL[NTOK * QSTR];     //  7840 B
    __shared__ __align__(16) u16 vL[HD * VSTR];       //  6656 B
    __shared__ __align__(16) u16 Pscr[4][16 * VSTR];  // 13312 B

    // XCD swizzle: keep the 4 head-blocks of a window on one XCD (x L2 reuse).
    // 8192 blocks = 8 XCDs * 1024 -> bijective.
    const int bh   = (blockIdx.x & 7) * 1024 + (blockIdx.x >> 3);
    const int b    = bh >> 2;
    const int h    = bh & 3;
    const int tid  = threadIdx.x;
    const int wave = tid >> 6;
    const int lane = tid & 63;
    const int l16  = lane & 15;
    const int quad = lane >> 4;

    const float* xb = x + (size_t)b * (NTOK * DIM);

    // ---- phase A: qkv GEMM (21 part-major units over 4 waves) ---------------
    {
        const int u0 = (wave * 21) >> 2;        // 0,5,10,15
        const int u1 = ((wave + 1) * 21) >> 2;  // 5,10,15,21
        int cached = -1;
        bf16x8 Bf[2][4];
        float  cb[2];
        for (int u = u0; u < u1; ++u) {
            const int part = u / 7;
            const int mt   = u - part * 7;
            if (part != cached) {
                const u16* wp = qkvw_bf + (size_t)part * DIM * DIM;
#pragma unroll
                for (int nt2 = 0; nt2 < 2; ++nt2) {
                    const int col = h * HD + nt2 * 16 + l16;
#pragma unroll
                    for (int ks = 0; ks < 4; ++ks)
                        Bf[nt2][ks] = *reinterpret_cast<const bf16x8*>(
                            wp + col * DIM + quad * 8 + ks * 32);
                    cb[nt2] = qkv_b[part * DIM + col];
                }
                cached = part;
            }
            int arow = mt * 16 + l16;
            if (arow > 97) arow = 97;          // pad rows duplicate row 97 (discarded)
            // A-frags straight from global x (f32 -> bf16)
            bf16x8 af[4];
#pragma unroll
            for (int ks = 0; ks < 4; ++ks) {
                const float* xr = xb + arow * DIM + quad * 8 + ks * 32;
                const float4 a0 = *reinterpret_cast<const float4*>(xr);
                const float4 a1 = *reinterpret_cast<const float4*>(xr + 4);
                bf16x8 a;
                a[0] = (bf16_t)a0.x; a[1] = (bf16_t)a0.y; a[2] = (bf16_t)a0.z; a[3] = (bf16_t)a0.w;
                a[4] = (bf16_t)a1.x; a[5] = (bf16_t)a1.y; a[6] = (bf16_t)a1.z; a[7] = (bf16_t)a1.w;
                af[ks] = a;
            }
            f32x4 acc0 = {0.f, 0.f, 0.f, 0.f};
            f32x4 acc1 = {0.f, 0.f, 0.f, 0.f};
#pragma unroll
            for (int ks = 0; ks < 4; ++ks) {
                acc0 = __builtin_amdgcn_mfma_f32_16x16x32_bf16(af[ks], Bf[0][ks], acc0, 0, 0, 0);
                acc1 = __builtin_amdgcn_mfma_f32_16x16x32_bf16(af[ks], Bf[1][ks], acc1, 0, 0, 0);
            }
            const int tokb = mt * 16 + quad * 4;
#pragma unroll
            for (int nt2 = 0; nt2 < 2; ++nt2) {
                const f32x4& acc = nt2 ? acc1 : acc0;
                const int d = nt2 * 16 + l16;          // 0..31 (head-local)
                const float cbv = cb[nt2];
                if (part == 0) {
#pragma unroll
                    for (int reg = 0; reg < 4; ++reg) {
                        int tok = tokb + reg;
                        if (tok < NTOK)
                            qL[tok * QSTR + d] = f2bf((acc[reg] + cbv) * SCALE);
                    }
                } else if (part == 1) {
#pragma unroll
                    for (int reg = 0; reg < 4; ++reg) {
                        int tok = tokb + reg;
                        if (tok < NTOK)
                            kL[tok * QSTR + d] = f2bf(acc[reg] + cbv);
                    }
                } else {
                    u16* vrow = &vL[d * VSTR];
                    if (tokb + 3 <= 97) {
                        u64 pack = 0;
#pragma unroll
                        for (int reg = 0; reg < 4; ++reg)
                            pack |= ((u64)f2bf(acc[reg] + cbv)) << (16 * reg);
                        *reinterpret_cast<u64*>(&vrow[tokb]) = pack;
                    } else if (tokb <= 97) {   // tokb == 96: tokens 96,97
                        u32 pack = (u32)f2bf(acc[0] + cbv) | ((u32)f2bf(acc[1] + cbv) << 16);
                        *reinterpret_cast<u32*>(&vrow[tokb]) = pack;
                    }
                }
            }
        }
    }
    __syncthreads();

    // ---- phase B: attention; waves split 7 mt tiles {w, w+4} ----------------
    {
        const u16* mbtp = mbT + ((size_t)((b & (NW - 1)) * HEADS + h)) * (NTOK * 128);
        u16* ps = &Pscr[wave][0];

        bf16x8 kf[7];
#pragma unroll
        for (int nj = 0; nj < 7; ++nj)
            kf[nj] = *reinterpret_cast<const bf16x8*>(&kL[(nj * 16 + l16) * QSTR + quad * 8]);

        for (int mi = 0; mi < 2; ++mi) {
            const int mt = wave + mi * 4;
            if (mt > 6) break;
            // issue mask+bias vector loads first so they overlap the MFMAs
            bf16x8 mrows[4];
#pragma unroll
            for (int reg = 0; reg < 4; ++reg) {
                int i  = mt * 16 + quad * 4 + reg;
                int ic = (i > 97) ? 97 : i;
                mrows[reg] = *reinterpret_cast<const bf16x8*>(&mbtp[ic * 128 + l16 * 8]);
            }
            bf16x8 qf = *reinterpret_cast<const bf16x8*>(&qL[(mt * 16 + l16) * QSTR + quad * 8]);
            f32x4 sacc[7];
#pragma unroll
            for (int nj = 0; nj < 7; ++nj) {
                f32x4 z = {0.f, 0.f, 0.f, 0.f};
                sacc[nj] = __builtin_amdgcn_mfma_f32_16x16x32_bf16(qf, kf[nj], z, 0, 0, 0);
            }
#pragma unroll
            for (int reg = 0; reg < 4; ++reg) {
                int i = mt * 16 + quad * 4 + reg;
                bool irow = (i < NTOK);
                float s[7];
#pragma unroll
                for (int nj = 0; nj < 7; ++nj) {
                    int j = nj * 16 + l16;
                    float val = -1e30f;
                    if (irow && j < NTOK)
                        val = sacc[nj][reg] + (float)mrows[reg][nj];
                    s[nj] = val;
                }
                float mx = s[0];
#pragma unroll
                for (int nj = 1; nj < 7; ++nj) mx = fmaxf(mx, s[nj]);
#pragma unroll
                for (int off = 1; off < 16; off <<= 1) mx = fmaxf(mx, __shfl_xor(mx, off));
                float p[7];
                float lsum = 0.f;
#pragma unroll
                for (int nj = 0; nj < 7; ++nj) {
                    float pv = (s[nj] > -1e29f) ? __expf(s[nj] - mx) : 0.f;
                    p[nj] = pv;
                    lsum += pv;
                }
#pragma unroll
                for (int off = 1; off < 16; off <<= 1) lsum += __shfl_xor(lsum, off);
                float rinv = 1.f / ((lsum > 0.f) ? lsum : 1.f);
#pragma unroll
                for (int nj = 0; nj < 7; ++nj) {
                    int j = nj * 16 + l16;
                    if (irow && j < NTOK)
                        ps[(quad * 4 + reg) * VSTR + j] = f2bf(p[nj] * rinv);
                }
            }
            // P (C-layout) -> A-frags via wave-private scratch (no barrier needed)
            bf16x8 pf[3];
#pragma unroll
            for (int ks = 0; ks < 3; ++ks)
                pf[ks] = *reinterpret_cast<const bf16x8*>(&ps[l16 * VSTR + quad * 8 + ks * 32]);
#pragma unroll
            for (int nt = 0; nt < 2; ++nt) {
                f32x4 oacc = {0.f, 0.f, 0.f, 0.f};
#pragma unroll
                for (int ks = 0; ks < 3; ++ks) {
                    bf16x8 vf = *reinterpret_cast<const bf16x8*>(
                        &vL[(nt * 16 + l16) * VSTR + quad * 8 + ks * 32]);
                    oacc = __builtin_amdgcn_mfma_f32_16x16x32_bf16(pf[ks], vf, oacc, 0, 0, 0);
                }
                int d = nt * 16 + l16;
                float v96 = bf2f(vL[d * VSTR + 96]);
                float v97 = bf2f(vL[d * VSTR + 97]);
#pragma unroll
                for (int reg = 0; reg < 4; ++reg) {
                    int i = mt * 16 + quad * 4 + reg;
                    if (i < NTOK) {
                        float p96 = bf2f(ps[(quad * 4 + reg) * VSTR + 96]);
                        float p97 = bf2f(ps[(quad * 4 + reg) * VSTR + 97]);
                        OG[((size_t)b * NTOK + i) * DIM + h * HD + d] =
                            f2bf(oacc[reg] + p96 * v96 + p97 * v97);
                    }
                }
            }
        }
    }
}

// ---------------- K2: proj GEMM, block = window, no LDS ----------------------
// wave w owns nt = {2w, 2w+1}; B-frags register-resident, A streamed b128.
__global__ __launch_bounds__(256, 4) void k_proj(
    const u16* __restrict__ OG, const u16* __restrict__ pw_bf,
    const float* __restrict__ proj_b, float* __restrict__ out)
{
    const int b    = blockIdx.x;
    const int tid  = threadIdx.x;
    const int wave = tid >> 6;
    const int lane = tid & 63;
    const int l16  = lane & 15;
    const int quad = lane >> 4;

    bf16x8 bw[2][4];
    float  pb[2];
#pragma unroll
    for (int nt2 = 0; nt2 < 2; ++nt2) {
        const int col = (wave * 2 + nt2) * 16 + l16;
#pragma unroll
        for (int ks = 0; ks < 4; ++ks)
            bw[nt2][ks] = *reinterpret_cast<const bf16x8*>(
                pw_bf + col * DIM + quad * 8 + ks * 32);
        pb[nt2] = proj_b[col];
    }
    const u16* ob = OG + (size_t)b * (NTOK * DIM);
    for (int mt = 0; mt < 7; ++mt) {
        int arow = mt * 16 + l16;
        if (arow > 97) arow = 97;
        bf16x8 af[4];
#pragma unroll
        for (int ks = 0; ks < 4; ++ks)
            af[ks] = *reinterpret_cast<const bf16x8*>(ob + arow * DIM + quad * 8 + ks * 32);
        f32x4 acc0 = {0.f, 0.f, 0.f, 0.f};
        f32x4 acc1 = {0.f, 0.f, 0.f, 0.f};
#pragma unroll
        for (int ks = 0; ks < 4; ++ks) {
            acc0 = __builtin_amdgcn_mfma_f32_16x16x32_bf16(af[ks], bw[0][ks], acc0, 0, 0, 0);
            acc1 = __builtin_amdgcn_mfma_f32_16x16x32_bf16(af[ks], bw[1][ks], acc1, 0, 0, 0);
        }
#pragma unroll
        for (int nt2 = 0; nt2 < 2; ++nt2) {
            const f32x4& acc = nt2 ? acc1 : acc0;
            const int col = (wave * 2 + nt2) * 16 + l16;
#pragma unroll
            for (int reg = 0; reg < 4; ++reg) {
                int row = mt * 16 + quad * 4 + reg;
                if (row < NTOK)
                    out[((size_t)b * NTOK + row) * DIM + col] = acc[reg] + pb[nt2];
            }
        }
    }
}

// ---------------- launch ------------------------------------------------------
extern "C" void kernel_launch(void* const* d_in, const int* in_sizes, int n_in,
                              void* d_out, int out_size, void* d_ws, size_t ws_size,
                              hipStream_t stream)
{
    const float* x       = (const float*)d_in[0];
    const float* mask    = (const float*)d_in[1];
    const float* qkv_w   = (const float*)d_in[2];
    const float* qkv_b   = (const float*)d_in[3];
    const float* proj_w  = (const float*)d_in[4];
    const float* proj_b  = (const float*)d_in[5];
    const float* bias_tb = (const float*)d_in[6];
    const int*   rel_idx = (const int*)d_in[7];
    float* out = (float*)d_out;

    char* ws = (char*)d_ws;
    u16* qkvw_bf = (u16*)(ws + 0);          //    98304 B
    u16* pw_bf   = (u16*)(ws + 98304);      //    32768 B
    u16* mbT     = (u16*)(ws + 131072);     //  6422528 B (64*4*98*128 u16)
    u16* OG      = (u16*)(ws + 6553600);    // 51380224 B (2048*98*128 u16)
    // total ~57.9 MB

    k0_prep<<<12800, 256, 0, stream>>>(qkv_w, proj_w, mask, bias_tb, rel_idx,
                                       qkvw_bf, pw_bf, mbT);
    k_attn<<<BWIN * HEADS, 256, 0, stream>>>(x, qkvw_bf, qkv_b, mbT, OG);
    k_proj<<<BWIN, 256, 0, stream>>>(OG, pw_bf, proj_b, out);
}

// Round 5
// 387.381 us; speedup vs baseline: 1.5784x; 1.0052x over previous
//
#include <hip/hip_runtime.h>
#include <stdint.h>

#define NTOK 98
#define DIM 128
#define HEADS 4
#define HD 32
#define BWIN 2048
#define NW 64
#define SCALE 0.17677669529663687f
#define QSTR 32    // qL/kL row stride in u16 (64 B) + XOR chunk swizzle (16-B granules)
#define VSTR 104   // vL / Pscr row stride in u16: 208 B -> 16B-aligned, 2-way banks (free)

typedef __bf16 bf16_t;
typedef bf16_t bf16x8 __attribute__((ext_vector_type(8)));
typedef float f32x4 __attribute__((ext_vector_type(4)));
typedef unsigned short u16;
typedef unsigned int u32;
typedef unsigned long long u64;

__device__ __forceinline__ u16 f2bf(float f) {
    union { bf16_t h; u16 u; } v; v.h = (bf16_t)f; return v.u;
}
__device__ __forceinline__ float bf2f(u16 b) {
    union { u16 u; bf16_t h; } v; v.u = b; return (float)v.h;
}
// swizzled u16 index into a stride-32 row-major [98][32] tile: 16-B chunk c of
// row r lives at chunk (c ^ (r&3)). Same formula on store and load.
__device__ __forceinline__ int qk_idx(int row, int d) {
    return row * QSTR + ((((d >> 3) ^ (row & 3)) << 3) | (d & 7));
}

// ---------------- K0: prep ----------------------------------------------------
// [0,49152)            qkv_w -> bf16
// [49152,65536)        proj_w -> bf16
// [65536,3276800)      mbT[w][h][i][l16][njp] = bf16(mask[w][i][j] + bias[rel_idx[i][j]][h])
//                      j = njp*16 + l16, njp in [0,8) (njp==7 or j>=98 -> 0)
// [3276800,6488064)    x (f32) -> xbf (bf16), 8 elems/thread
__global__ void k0_prep(const float* __restrict__ qkv_w, const float* __restrict__ proj_w,
                        const float* __restrict__ mask,
                        const float* __restrict__ bias_table, const int* __restrict__ rel_idx,
                        const float* __restrict__ x,
                        u16* __restrict__ qkvw_bf, u16* __restrict__ pw_bf,
                        u16* __restrict__ mbT, u16* __restrict__ xbf)
{
    int t = blockIdx.x * 256 + threadIdx.x;
    if (t < 49152) {
        qkvw_bf[t] = f2bf(qkv_w[t]);
    } else if (t < 65536) {
        int r = t - 49152;
        pw_bf[r] = f2bf(proj_w[r]);
    } else if (t < 3276800) {
        int r = t - 65536;                  // [0, 64*4*98*128)
        int w    = r / 50176;               // 4*98*128
        int rem  = r - w * 50176;
        int hh   = rem / 12544;             // 98*128
        int rem2 = rem - hh * 12544;
        int i    = rem2 >> 7;
        int c    = rem2 & 127;
        int l16  = c >> 3;
        int njp  = c & 7;
        int j    = njp * 16 + l16;
        float val = 0.f;
        if (njp < 7 && j < NTOK)
            val = mask[w * 9604 + i * NTOK + j] + bias_table[rel_idx[i * NTOK + j] * HEADS + hh];
        mbT[r] = f2bf(val);
    } else if (t < 6488064) {
        size_t idx = (size_t)(t - 3276800) * 8;   // 8 floats -> 8 bf16
        const float4 a0 = *reinterpret_cast<const float4*>(x + idx);
        const float4 a1 = *reinterpret_cast<const float4*>(x + idx + 4);
        u64 p0 = (u64)f2bf(a0.x) | ((u64)f2bf(a0.y) << 16) |
                 ((u64)f2bf(a0.z) << 32) | ((u64)f2bf(a0.w) << 48);
        u64 p1 = (u64)f2bf(a1.x) | ((u64)f2bf(a1.y) << 16) |
                 ((u64)f2bf(a1.z) << 32) | ((u64)f2bf(a1.w) << 48);
        *reinterpret_cast<u64*>(&xbf[idx])     = p0;
        *reinterpret_cast<u64*>(&xbf[idx + 4]) = p1;
    }
}

// ---------------- K1: qkv GEMM + attention, block = (window, head) -----------
// 256 threads (4 waves), LDS 32512 B -> 5 blocks/CU (20 waves/CU).
// Phase A: qkv GEMM for this head's 32 cols x 3 parts; A-frags are direct b128
//          loads from pre-converted xbf; B-frags register-cached per part.
// Phase B: attention (verified body), O -> global bf16 OG[b][i][h*32+d].
__global__ __launch_bounds__(256, 5) void k_attn(
    const u16* __restrict__ xbf, const u16* __restrict__ qkvw_bf,
    const float* __restrict__ qkv_b, const u16* __restrict__ mbT,
    u16* __restrict__ OG)
{
    __shared__ __align__(16) u16 qL[NTOK * QSTR];     //  6272 B
    __shared__ __align__(16) u16 kL[NTOK * QSTR];     //  6272 B
    __shared__ __align__(16) u16 vL[HD * VSTR];       //  6656 B
    __shared__ __align__(16) u16 Pscr[4][16 * VSTR];  // 13312 B

    // XCD swizzle: keep the 4 head-blocks of a window on one XCD (x L2 reuse).
    // 8192 blocks = 8 XCDs * 1024 -> bijective.
    const int bh   = (blockIdx.x & 7) * 1024 + (blockIdx.x >> 3);
    const int b    = bh >> 2;
    const int h    = bh & 3;
    const int tid  = threadIdx.x;
    const int wave = tid >> 6;
    const int lane = tid & 63;
    const int l16  = lane & 15;
    const int quad = lane >> 4;

    const u16* xb = xbf + (size_t)b * (NTOK * DIM);

    // ---- phase A: qkv GEMM (21 part-major units over 4 waves) ---------------
    {
        const int u0 = (wave * 21) >> 2;        // 0,5,10,15
        const int u1 = ((wave + 1) * 21) >> 2;  // 5,10,15,21
        int cached = -1;
        bf16x8 Bf[2][4];
        float  cb[2];
        for (int u = u0; u < u1; ++u) {
            const int part = u / 7;
            const int mt   = u - part * 7;
            if (part != cached) {
                const u16* wp = qkvw_bf + (size_t)part * DIM * DIM;
#pragma unroll
                for (int nt2 = 0; nt2 < 2; ++nt2) {
                    const int col = h * HD + nt2 * 16 + l16;
#pragma unroll
                    for (int ks = 0; ks < 4; ++ks)
                        Bf[nt2][ks] = *reinterpret_cast<const bf16x8*>(
                            wp + col * DIM + quad * 8 + ks * 32);
                    cb[nt2] = qkv_b[part * DIM + col];
                }
                cached = part;
            }
            int arow = mt * 16 + l16;
            if (arow > 97) arow = 97;          // pad rows duplicate row 97 (discarded)
            bf16x8 af[4];
#pragma unroll
            for (int ks = 0; ks < 4; ++ks)
                af[ks] = *reinterpret_cast<const bf16x8*>(
                    xb + arow * DIM + quad * 8 + ks * 32);
            f32x4 acc0 = {0.f, 0.f, 0.f, 0.f};
            f32x4 acc1 = {0.f, 0.f, 0.f, 0.f};
#pragma unroll
            for (int ks = 0; ks < 4; ++ks) {
                acc0 = __builtin_amdgcn_mfma_f32_16x16x32_bf16(af[ks], Bf[0][ks], acc0, 0, 0, 0);
                acc1 = __builtin_amdgcn_mfma_f32_16x16x32_bf16(af[ks], Bf[1][ks], acc1, 0, 0, 0);
            }
            const int tokb = mt * 16 + quad * 4;
#pragma unroll
            for (int nt2 = 0; nt2 < 2; ++nt2) {
                const f32x4& acc = nt2 ? acc1 : acc0;
                const int d = nt2 * 16 + l16;          // 0..31 (head-local)
                const float cbv = cb[nt2];
                if (part == 0) {
#pragma unroll
                    for (int reg = 0; reg < 4; ++reg) {
                        int tok = tokb + reg;
                        if (tok < NTOK)
                            qL[qk_idx(tok, d)] = f2bf((acc[reg] + cbv) * SCALE);
                    }
                } else if (part == 1) {
#pragma unroll
                    for (int reg = 0; reg < 4; ++reg) {
                        int tok = tokb + reg;
                        if (tok < NTOK)
                            kL[qk_idx(tok, d)] = f2bf(acc[reg] + cbv);
                    }
                } else {
                    u16* vrow = &vL[d * VSTR];
                    if (tokb + 3 <= 97) {
                        u64 pack = 0;
#pragma unroll
                        for (int reg = 0; reg < 4; ++reg)
                            pack |= ((u64)f2bf(acc[reg] + cbv)) << (16 * reg);
                        *reinterpret_cast<u64*>(&vrow[tokb]) = pack;
                    } else if (tokb <= 97) {   // tokb == 96: tokens 96,97
                        u32 pack = (u32)f2bf(acc[0] + cbv) | ((u32)f2bf(acc[1] + cbv) << 16);
                        *reinterpret_cast<u32*>(&vrow[tokb]) = pack;
                    }
                }
            }
        }
    }
    __syncthreads();

    // ---- phase B: attention; waves split 7 mt tiles {w, w+4} ----------------
    {
        const u16* mbtp = mbT + ((size_t)((b & (NW - 1)) * HEADS + h)) * (NTOK * 128);
        u16* ps = &Pscr[wave][0];
        const int qko = ((quad ^ (l16 & 3)) << 3);   // swizzled chunk offset for qL/kL reads

        bf16x8 kf[7];
#pragma unroll
        for (int nj = 0; nj < 7; ++nj)
            kf[nj] = *reinterpret_cast<const bf16x8*>(&kL[(nj * 16 + l16) * QSTR + qko]);

        for (int mi = 0; mi < 2; ++mi) {
            const int mt = wave + mi * 4;
            if (mt > 6) break;
            // issue mask+bias vector loads first so they overlap the MFMAs
            bf16x8 mrows[4];
#pragma unroll
            for (int reg = 0; reg < 4; ++reg) {
                int i  = mt * 16 + quad * 4 + reg;
                int ic = (i > 97) ? 97 : i;
                mrows[reg] = *reinterpret_cast<const bf16x8*>(&mbtp[ic * 128 + l16 * 8]);
            }
            bf16x8 qf = *reinterpret_cast<const bf16x8*>(&qL[(mt * 16 + l16) * QSTR + qko]);
            f32x4 sacc[7];
#pragma unroll
            for (int nj = 0; nj < 7; ++nj) {
                f32x4 z = {0.f, 0.f, 0.f, 0.f};
                sacc[nj] = __builtin_amdgcn_mfma_f32_16x16x32_bf16(qf, kf[nj], z, 0, 0, 0);
            }
#pragma unroll
            for (int reg = 0; reg < 4; ++reg) {
                int i = mt * 16 + quad * 4 + reg;
                bool irow = (i < NTOK);
                float s[7];
#pragma unroll
                for (int nj = 0; nj < 7; ++nj) {
                    int j = nj * 16 + l16;
                    float val = -1e30f;
                    if (irow && j < NTOK)
                        val = sacc[nj][reg] + (float)mrows[reg][nj];
                    s[nj] = val;
                }
                float mx = s[0];
#pragma unroll
                for (int nj = 1; nj < 7; ++nj) mx = fmaxf(mx, s[nj]);
#pragma unroll
                for (int off = 1; off < 16; off <<= 1) mx = fmaxf(mx, __shfl_xor(mx, off));
                float p[7];
                float lsum = 0.f;
#pragma unroll
                for (int nj = 0; nj < 7; ++nj) {
                    float pv = (s[nj] > -1e29f) ? __expf(s[nj] - mx) : 0.f;
                    p[nj] = pv;
                    lsum += pv;
                }
#pragma unroll
                for (int off = 1; off < 16; off <<= 1) lsum += __shfl_xor(lsum, off);
                float rinv = 1.f / ((lsum > 0.f) ? lsum : 1.f);
#pragma unroll
                for (int nj = 0; nj < 7; ++nj) {
                    int j = nj * 16 + l16;
                    if (irow && j < NTOK)
                        ps[(quad * 4 + reg) * VSTR + j] = f2bf(p[nj] * rinv);
                }
            }
            // P (C-layout) -> A-frags via wave-private scratch (no barrier needed)
            bf16x8 pf[3];
#pragma unroll
            for (int ks = 0; ks < 3; ++ks)
                pf[ks] = *reinterpret_cast<const bf16x8*>(&ps[l16 * VSTR + quad * 8 + ks * 32]);
#pragma unroll
            for (int nt = 0; nt < 2; ++nt) {
                f32x4 oacc = {0.f, 0.f, 0.f, 0.f};
#pragma unroll
                for (int ks = 0; ks < 3; ++ks) {
                    bf16x8 vf = *reinterpret_cast<const bf16x8*>(
                        &vL[(nt * 16 + l16) * VSTR + quad * 8 + ks * 32]);
                    oacc = __builtin_amdgcn_mfma_f32_16x16x32_bf16(pf[ks], vf, oacc, 0, 0, 0);
                }
                int d = nt * 16 + l16;
                float v96 = bf2f(vL[d * VSTR + 96]);
                float v97 = bf2f(vL[d * VSTR + 97]);
#pragma unroll
                for (int reg = 0; reg < 4; ++reg) {
                    int i = mt * 16 + quad * 4 + reg;
                    if (i < NTOK) {
                        float p96 = bf2f(ps[(quad * 4 + reg) * VSTR + 96]);
                        float p97 = bf2f(ps[(quad * 4 + reg) * VSTR + 97]);
                        OG[((size_t)b * NTOK + i) * DIM + h * HD + d] =
                            f2bf(oacc[reg] + p96 * v96 + p97 * v97);
                    }
                }
            }
        }
    }
}

// ---------------- K2: proj GEMM, block = window, no LDS ----------------------
// wave w owns nt = {2w, 2w+1}; B-frags register-resident, A streamed b128.
__global__ __launch_bounds__(256, 4) void k_proj(
    const u16* __restrict__ OG, const u16* __restrict__ pw_bf,
    const float* __restrict__ proj_b, float* __restrict__ out)
{
    const int b    = blockIdx.x;
    const int tid  = threadIdx.x;
    const int wave = tid >> 6;
    const int lane = tid & 63;
    const int l16  = lane & 15;
    const int quad = lane >> 4;

    bf16x8 bw[2][4];
    float  pb[2];
#pragma unroll
    for (int nt2 = 0; nt2 < 2; ++nt2) {
        const int col = (wave * 2 + nt2) * 16 + l16;
#pragma unroll
        for (int ks = 0; ks < 4; ++ks)
            bw[nt2][ks] = *reinterpret_cast<const bf16x8*>(
                pw_bf + col * DIM + quad * 8 + ks * 32);
        pb[nt2] = proj_b[col];
    }
    const u16* ob = OG + (size_t)b * (NTOK * DIM);
    for (int mt = 0; mt < 7; ++mt) {
        int arow = mt * 16 + l16;
        if (arow > 97) arow = 97;
        bf16x8 af[4];
#pragma unroll
        for (int ks = 0; ks < 4; ++ks)
            af[ks] = *reinterpret_cast<const bf16x8*>(ob + arow * DIM + quad * 8 + ks * 32);
        f32x4 acc0 = {0.f, 0.f, 0.f, 0.f};
        f32x4 acc1 = {0.f, 0.f, 0.f, 0.f};
#pragma unroll
        for (int ks = 0; ks < 4; ++ks) {
            acc0 = __builtin_amdgcn_mfma_f32_16x16x32_bf16(af[ks], bw[0][ks], acc0, 0, 0, 0);
            acc1 = __builtin_amdgcn_mfma_f32_16x16x32_bf16(af[ks], bw[1][ks], acc1, 0, 0, 0);
        }
#pragma unroll
        for (int nt2 = 0; nt2 < 2; ++nt2) {
            const f32x4& acc = nt2 ? acc1 : acc0;
            const int col = (wave * 2 + nt2) * 16 + l16;
#pragma unroll
            for (int reg = 0; reg < 4; ++reg) {
                int row = mt * 16 + quad * 4 + reg;
                if (row < NTOK)
                    out[((size_t)b * NTOK + row) * DIM + col] = acc[reg] + pb[nt2];
            }
        }
    }
}

// ---------------- launch ------------------------------------------------------
extern "C" void kernel_launch(void* const* d_in, const int* in_sizes, int n_in,
                              void* d_out, int out_size, void* d_ws, size_t ws_size,
                              hipStream_t stream)
{
    const float* x       = (const float*)d_in[0];
    const float* mask    = (const float*)d_in[1];
    const float* qkv_w   = (const float*)d_in[2];
    const float* qkv_b   = (const float*)d_in[3];
    const float* proj_w  = (const float*)d_in[4];
    const float* proj_b  = (const float*)d_in[5];
    const float* bias_tb = (const float*)d_in[6];
    const int*   rel_idx = (const int*)d_in[7];
    float* out = (float*)d_out;

    char* ws = (char*)d_ws;
    u16* qkvw_bf = (u16*)(ws + 0);          //    98304 B
    u16* pw_bf   = (u16*)(ws + 98304);      //    32768 B
    u16* mbT     = (u16*)(ws + 131072);     //  6422528 B (64*4*98*128 u16)
    u16* xbf     = (u16*)(ws + 6553600);    // 51380224 B (2048*98*128 u16)
    u16* OG      = (u16*)(ws + 57933824);   // 51380224 B (2048*98*128 u16)
    // total ~109.3 MB

    k0_prep<<<25344, 256, 0, stream>>>(qkv_w, proj_w, mask, bias_tb, rel_idx, x,
                                       qkvw_bf, pw_bf, mbT, xbf);
    k_attn<<<BWIN * HEADS, 256, 0, stream>>>(xbf, qkvw_bf, qkv_b, mbT, OG);
    k_proj<<<BWIN, 256, 0, stream>>>(OG, pw_bf, proj_b, out);
}

// Round 7
// 367.210 us; speedup vs baseline: 1.6651x; 1.0549x over previous
//
#include <hip/hip_runtime.h>
#include <stdint.h>

#define NTOK 98
#define DIM 128
#define HEADS 4
#define HD 32
#define BWIN 2048
#define NW 64
#define SCALE 0.17677669529663687f
#define QSTR 32    // qL/kL row stride in u16 (64 B) + XOR chunk swizzle (16-B granules)
#define VSTR 104   // vL / Pscr row stride in u16: 208 B -> 16B-aligned, 2-way banks (free)

typedef __bf16 bf16_t;
typedef bf16_t bf16x8 __attribute__((ext_vector_type(8)));
typedef float f32x4 __attribute__((ext_vector_type(4)));
typedef unsigned short u16;
typedef unsigned int u32;
typedef unsigned long long u64;

__device__ __forceinline__ u16 f2bf(float f) {
    union { bf16_t h; u16 u; } v; v.h = (bf16_t)f; return v.u;
}
__device__ __forceinline__ float bf2f(u16 b) {
    union { u16 u; bf16_t h; } v; v.u = b; return (float)v.h;
}
// swizzled u16 index into a stride-32 row-major [98][32] tile: 16-B chunk c of
// row r lives at chunk (c ^ (r&3)). Same formula on store and load.
__device__ __forceinline__ int qk_idx(int row, int d) {
    return row * QSTR + ((((d >> 3) ^ (row & 3)) << 3) | (d & 7));
}

// ---------------- K0: prep ----------------------------------------------------
// [0,49152)            qkv_w -> bf16
// [49152,65536)        proj_w -> bf16
// [65536,3276800)      mbT[w][h][i][l16][njp] = bf16(mask[w][i][j] + bias[rel_idx[i][j]][h])
//                      j = njp*16 + l16, njp in [0,8); PAD entries = -1e30
//                      (njp==7 or j>=98) -> softmax needs no masking branches
// [3276800,6488064)    x (f32) -> xbf (bf16), 8 elems/thread
__global__ void k0_prep(const float* __restrict__ qkv_w, const float* __restrict__ proj_w,
                        const float* __restrict__ mask,
                        const float* __restrict__ bias_table, const int* __restrict__ rel_idx,
                        const float* __restrict__ x,
                        u16* __restrict__ qkvw_bf, u16* __restrict__ pw_bf,
                        u16* __restrict__ mbT, u16* __restrict__ xbf)
{
    int t = blockIdx.x * 256 + threadIdx.x;
    if (t < 49152) {
        qkvw_bf[t] = f2bf(qkv_w[t]);
    } else if (t < 65536) {
        int r = t - 49152;
        pw_bf[r] = f2bf(proj_w[r]);
    } else if (t < 3276800) {
        int r = t - 65536;                  // [0, 64*4*98*128)
        int w    = r / 50176;               // 4*98*128
        int rem  = r - w * 50176;
        int hh   = rem / 12544;             // 98*128
        int rem2 = rem - hh * 12544;
        int i    = rem2 >> 7;
        int c    = rem2 & 127;
        int l16  = c >> 3;
        int njp  = c & 7;
        int j    = njp * 16 + l16;
        float val = -1e30f;                 // pad -> exp() underflows to 0
        if (njp < 7 && j < NTOK)
            val = mask[w * 9604 + i * NTOK + j] + bias_table[rel_idx[i * NTOK + j] * HEADS + hh];
        mbT[r] = f2bf(val);
    } else if (t < 6488064) {
        size_t idx = (size_t)(t - 3276800) * 8;   // 8 floats -> 8 bf16
        const float4 a0 = *reinterpret_cast<const float4*>(x + idx);
        const float4 a1 = *reinterpret_cast<const float4*>(x + idx + 4);
        u64 p0 = (u64)f2bf(a0.x) | ((u64)f2bf(a0.y) << 16) |
                 ((u64)f2bf(a0.z) << 32) | ((u64)f2bf(a0.w) << 48);
        u64 p1 = (u64)f2bf(a1.x) | ((u64)f2bf(a1.y) << 16) |
                 ((u64)f2bf(a1.z) << 32) | ((u64)f2bf(a1.w) << 48);
        *reinterpret_cast<u64*>(&xbf[idx])     = p0;
        *reinterpret_cast<u64*>(&xbf[idx + 4]) = p1;
    }
}

// ---------------- K1: qkv GEMM + attention, block = (window, head) -----------
// 256 threads (4 waves), LDS 32512 B -> 5 blocks/CU (20 waves/CU).
// Phase A: qkv GEMM for this head's 32 cols x 3 parts; A-frags are direct b128
//          loads from pre-converted xbf; B-frags register-cached per part.
// Phase B: attention, branchless softmax with deferred normalization;
//          O -> global bf16 OG[b][i][h*32+d].
__global__ __launch_bounds__(256, 5) void k_attn(
    const u16* __restrict__ xbf, const u16* __restrict__ qkvw_bf,
    const float* __restrict__ qkv_b, const u16* __restrict__ mbT,
    u16* __restrict__ OG)
{
    __shared__ __align__(16) u16 qL[NTOK * QSTR];     //  6272 B
    __shared__ __align__(16) u16 kL[NTOK * QSTR];     //  6272 B
    __shared__ __align__(16) u16 vL[HD * VSTR];       //  6656 B
    __shared__ __align__(16) u16 Pscr[4][16 * VSTR];  // 13312 B

    // XCD swizzle: keep the 4 head-blocks of a window on one XCD (x L2 reuse).
    // 8192 blocks = 8 XCDs * 1024 -> bijective. Window w lands on XCD w>>8.
    const int bh   = (blockIdx.x & 7) * 1024 + (blockIdx.x >> 3);
    const int b    = bh >> 2;
    const int h    = bh & 3;
    const int tid  = threadIdx.x;
    const int wave = tid >> 6;
    const int lane = tid & 63;
    const int l16  = lane & 15;
    const int quad = lane >> 4;

    const u16* xb = xbf + (size_t)b * (NTOK * DIM);

    // ---- phase A: qkv GEMM (21 part-major units over 4 waves) ---------------
    {
        const int u0 = (wave * 21) >> 2;        // 0,5,10,15
        const int u1 = ((wave + 1) * 21) >> 2;  // 5,10,15,21
        int cached = -1;
        bf16x8 Bf[2][4];
        float  cb[2];
        for (int u = u0; u < u1; ++u) {
            const int part = u / 7;
            const int mt   = u - part * 7;
            if (part != cached) {
                const u16* wp = qkvw_bf + (size_t)part * DIM * DIM;
#pragma unroll
                for (int nt2 = 0; nt2 < 2; ++nt2) {
                    const int col = h * HD + nt2 * 16 + l16;
#pragma unroll
                    for (int ks = 0; ks < 4; ++ks)
                        Bf[nt2][ks] = *reinterpret_cast<const bf16x8*>(
                            wp + col * DIM + quad * 8 + ks * 32);
                    cb[nt2] = qkv_b[part * DIM + col];
                }
                cached = part;
            }
            int arow = mt * 16 + l16;
            if (arow > 97) arow = 97;          // pad rows duplicate row 97 (discarded)
            bf16x8 af[4];
#pragma unroll
            for (int ks = 0; ks < 4; ++ks)
                af[ks] = *reinterpret_cast<const bf16x8*>(
                    xb + arow * DIM + quad * 8 + ks * 32);
            f32x4 acc0 = {0.f, 0.f, 0.f, 0.f};
            f32x4 acc1 = {0.f, 0.f, 0.f, 0.f};
            __builtin_amdgcn_s_setprio(1);
#pragma unroll
            for (int ks = 0; ks < 4; ++ks) {
                acc0 = __builtin_amdgcn_mfma_f32_16x16x32_bf16(af[ks], Bf[0][ks], acc0, 0, 0, 0);
                acc1 = __builtin_amdgcn_mfma_f32_16x16x32_bf16(af[ks], Bf[1][ks], acc1, 0, 0, 0);
            }
            __builtin_amdgcn_s_setprio(0);
            const int tokb = mt * 16 + quad * 4;
#pragma unroll
            for (int nt2 = 0; nt2 < 2; ++nt2) {
                const f32x4& acc = nt2 ? acc1 : acc0;
                const int d = nt2 * 16 + l16;          // 0..31 (head-local)
                const float cbv = cb[nt2];
                if (part == 0) {
#pragma unroll
                    for (int reg = 0; reg < 4; ++reg) {
                        int tok = tokb + reg;
                        if (tok < NTOK)
                            qL[qk_idx(tok, d)] = f2bf((acc[reg] + cbv) * SCALE);
                    }
                } else if (part == 1) {
#pragma unroll
                    for (int reg = 0; reg < 4; ++reg) {
                        int tok = tokb + reg;
                        if (tok < NTOK)
                            kL[qk_idx(tok, d)] = f2bf(acc[reg] + cbv);
                    }
                } else {
                    u16* vrow = &vL[d * VSTR];
                    if (tokb + 3 <= 97) {
                        u64 pack = 0;
#pragma unroll
                        for (int reg = 0; reg < 4; ++reg)
                            pack |= ((u64)f2bf(acc[reg] + cbv)) << (16 * reg);
                        *reinterpret_cast<u64*>(&vrow[tokb]) = pack;
                    } else if (tokb <= 97) {   // tokb == 96: tokens 96,97
                        u32 pack = (u32)f2bf(acc[0] + cbv) | ((u32)f2bf(acc[1] + cbv) << 16);
                        *reinterpret_cast<u32*>(&vrow[tokb]) = pack;
                    }
                }
            }
        }
    }
    __syncthreads();

    // ---- phase B: attention; waves split 7 mt tiles {w, w+4} ----------------
    // Branchless softmax (mbT pads are -1e30 -> exp()=0); P stored UNNORMALIZED,
    // row-inverse applied once at the O-write. K/Q LDS row indices are CLAMPED
    // to 97 (rows 98..111 would read OOB garbage; clamped duplicates get -1e30
    // from mbT pads -> exp()=0, so they never contaminate max/lsum).
    {
        const u16* mbtp = mbT + ((size_t)((b & (NW - 1)) * HEADS + h)) * (NTOK * 128);
        u16* ps = &Pscr[wave][0];
        const int qko = ((quad ^ (l16 & 3)) << 3);   // swizzled chunk offset for qL/kL reads

        bf16x8 kf[7];
#pragma unroll
        for (int nj = 0; nj < 7; ++nj) {
            int krow = nj * 16 + l16;
            if (krow > 97) krow = 97;          // clamp: avoid OOB-garbage K rows
            kf[nj] = *reinterpret_cast<const bf16x8*>(&kL[krow * QSTR + qko]);
        }

        for (int mi = 0; mi < 2; ++mi) {
            const int mt = wave + mi * 4;
            if (mt > 6) break;
            // issue mask+bias vector loads first so they overlap the MFMAs
            bf16x8 mrows[4];
#pragma unroll
            for (int reg = 0; reg < 4; ++reg) {
                int i  = mt * 16 + quad * 4 + reg;
                int ic = (i > 97) ? 97 : i;
                mrows[reg] = *reinterpret_cast<const bf16x8*>(&mbtp[ic * 128 + l16 * 8]);
            }
            int qrow = mt * 16 + l16;
            if (qrow > 97) qrow = 97;          // clamp: duplicate rows, outputs discarded
            bf16x8 qf = *reinterpret_cast<const bf16x8*>(&qL[qrow * QSTR + qko]);
            f32x4 sacc[7];
            __builtin_amdgcn_s_setprio(1);
#pragma unroll
            for (int nj = 0; nj < 7; ++nj) {
                f32x4 z = {0.f, 0.f, 0.f, 0.f};
                sacc[nj] = __builtin_amdgcn_mfma_f32_16x16x32_bf16(qf, kf[nj], z, 0, 0, 0);
            }
            __builtin_amdgcn_s_setprio(0);
            float rin[4];
#pragma unroll
            for (int reg = 0; reg < 4; ++reg) {
                float s[7];
#pragma unroll
                for (int nj = 0; nj < 7; ++nj)
                    s[nj] = sacc[nj][reg] + (float)mrows[reg][nj];
                float mx = fmaxf(fmaxf(fmaxf(s[0], s[1]), fmaxf(s[2], s[3])),
                                 fmaxf(fmaxf(s[4], s[5]), s[6]));
#pragma unroll
                for (int off = 1; off < 16; off <<= 1) mx = fmaxf(mx, __shfl_xor(mx, off));
                float p[7];
                float lsum = 0.f;
#pragma unroll
                for (int nj = 0; nj < 7; ++nj) {
                    p[nj] = __expf(s[nj] - mx);
                    lsum += p[nj];
                }
                // stores no longer gated by the lsum reduction
                u16* psr = &ps[(quad * 4 + reg) * VSTR];
#pragma unroll
                for (int nj = 0; nj < 6; ++nj)
                    psr[nj * 16 + l16] = f2bf(p[nj]);
                if (l16 < 8) psr[96 + l16] = f2bf(p[6]);   // j=96..103 (98+ are zeros, unused)
#pragma unroll
                for (int off = 1; off < 16; off <<= 1) lsum += __shfl_xor(lsum, off);
                rin[reg] = 1.f / lsum;
            }
            // P (C-layout) -> A-frags via wave-private scratch (no barrier needed)
            bf16x8 pf[3];
#pragma unroll
            for (int ks = 0; ks < 3; ++ks)
                pf[ks] = *reinterpret_cast<const bf16x8*>(&ps[l16 * VSTR + quad * 8 + ks * 32]);
#pragma unroll
            for (int nt = 0; nt < 2; ++nt) {
                f32x4 oacc = {0.f, 0.f, 0.f, 0.f};
                __builtin_amdgcn_s_setprio(1);
#pragma unroll
                for (int ks = 0; ks < 3; ++ks) {
                    bf16x8 vf = *reinterpret_cast<const bf16x8*>(
                        &vL[(nt * 16 + l16) * VSTR + quad * 8 + ks * 32]);
                    oacc = __builtin_amdgcn_mfma_f32_16x16x32_bf16(pf[ks], vf, oacc, 0, 0, 0);
                }
                __builtin_amdgcn_s_setprio(0);
                int d = nt * 16 + l16;
                float v96 = bf2f(vL[d * VSTR + 96]);
                float v97 = bf2f(vL[d * VSTR + 97]);
#pragma unroll
                for (int reg = 0; reg < 4; ++reg) {
                    int i = mt * 16 + quad * 4 + reg;
                    if (i < NTOK) {
                        float p96 = bf2f(ps[(quad * 4 + reg) * VSTR + 96]);
                        float p97 = bf2f(ps[(quad * 4 + reg) * VSTR + 97]);
                        OG[((size_t)b * NTOK + i) * DIM + h * HD + d] =
                            f2bf((oacc[reg] + p96 * v96 + p97 * v97) * rin[reg]);
                    }
                }
            }
        }
    }
}

// ---------------- K2: proj GEMM, block = window, no LDS ----------------------
// wave w owns nt = {2w, 2w+1}; B-frags register-resident, A streamed b128.
// XCD swizzle matches k_attn's writer mapping: window w -> XCD w>>8, so OG
// reads hit the L2 that produced them.
__global__ __launch_bounds__(256, 4) void k_proj(
    const u16* __restrict__ OG, const u16* __restrict__ pw_bf,
    const float* __restrict__ proj_b, float* __restrict__ out)
{
    const int b    = ((blockIdx.x & 7) << 8) + (blockIdx.x >> 3);   // 2048 = 8*256, bijective
    const int tid  = threadIdx.x;
    const int wave = tid >> 6;
    const int lane = tid & 63;
    const int l16  = lane & 15;
    const int quad = lane >> 4;

    bf16x8 bw[2][4];
    float  pb[2];
#pragma unroll
    for (int nt2 = 0; nt2 < 2; ++nt2) {
        const int col = (wave * 2 + nt2) * 16 + l16;
#pragma unroll
        for (int ks = 0; ks < 4; ++ks)
            bw[nt2][ks] = *reinterpret_cast<const bf16x8*>(
                pw_bf + col * DIM + quad * 8 + ks * 32);
        pb[nt2] = proj_b[col];
    }
    const u16* ob = OG + (size_t)b * (NTOK * DIM);
    for (int mt = 0; mt < 7; ++mt) {
        int arow = mt * 16 + l16;
        if (arow > 97) arow = 97;
        bf16x8 af[4];
#pragma unroll
        for (int ks = 0; ks < 4; ++ks)
            af[ks] = *reinterpret_cast<const bf16x8*>(ob + arow * DIM + quad * 8 + ks * 32);
        f32x4 acc0 = {0.f, 0.f, 0.f, 0.f};
        f32x4 acc1 = {0.f, 0.f, 0.f, 0.f};
#pragma unroll
        for (int ks = 0; ks < 4; ++ks) {
            acc0 = __builtin_amdgcn_mfma_f32_16x16x32_bf16(af[ks], bw[0][ks], acc0, 0, 0, 0);
            acc1 = __builtin_amdgcn_mfma_f32_16x16x32_bf16(af[ks], bw[1][ks], acc1, 0, 0, 0);
        }
#pragma unroll
        for (int nt2 = 0; nt2 < 2; ++nt2) {
            const f32x4& acc = nt2 ? acc1 : acc0;
            const int col = (wave * 2 + nt2) * 16 + l16;
#pragma unroll
            for (int reg = 0; reg < 4; ++reg) {
                int row = mt * 16 + quad * 4 + reg;
                if (row < NTOK)
                    out[((size_t)b * NTOK + row) * DIM + col] = acc[reg] + pb[nt2];
            }
        }
    }
}

// ---------------- launch ------------------------------------------------------
extern "C" void kernel_launch(void* const* d_in, const int* in_sizes, int n_in,
                              void* d_out, int out_size, void* d_ws, size_t ws_size,
                              hipStream_t stream)
{
    const float* x       = (const float*)d_in[0];
    const float* mask    = (const float*)d_in[1];
    const float* qkv_w   = (const float*)d_in[2];
    const float* qkv_b   = (const float*)d_in[3];
    const float* proj_w  = (const float*)d_in[4];
    const float* proj_b  = (const float*)d_in[5];
    const float* bias_tb = (const float*)d_in[6];
    const int*   rel_idx = (const int*)d_in[7];
    float* out = (float*)d_out;

    char* ws = (char*)d_ws;
    u16* qkvw_bf = (u16*)(ws + 0);          //    98304 B
    u16* pw_bf   = (u16*)(ws + 98304);      //    32768 B
    u16* mbT     = (u16*)(ws + 131072);     //  6422528 B (64*4*98*128 u16)
    u16* xbf     = (u16*)(ws + 6553600);    // 51380224 B (2048*98*128 u16)
    u16* OG      = (u16*)(ws + 57933824);   // 51380224 B (2048*98*128 u16)
    // total ~109.3 MB

    k0_prep<<<25344, 256, 0, stream>>>(qkv_w, proj_w, mask, bias_tb, rel_idx, x,
                                       qkvw_bf, pw_bf, mbT, xbf);
    k_attn<<<BWIN * HEADS, 256, 0, stream>>>(xbf, qkvw_bf, qkv_b, mbT, OG);
    k_proj<<<BWIN, 256, 0, stream>>>(OG, pw_bf, proj_b, out);
}

// Round 8
// 356.101 us; speedup vs baseline: 1.7171x; 1.0312x over previous
//
#include <hip/hip_runtime.h>
#include <stdint.h>

#define NTOK 98
#define DIM 128
#define HEADS 4
#define HD 32
#define BWIN 2048
#define NW 64
#define SCALE 0.17677669529663687f
#define QSTR 32    // qL/kL row stride in u16 (64 B) + XOR chunk swizzle (16-B granules)
#define VSTR 104   // vL / Pscr row stride in u16: 208 B -> 16B-aligned, 2-way banks (free)

typedef __bf16 bf16_t;
typedef bf16_t bf16x8 __attribute__((ext_vector_type(8)));
typedef float f32x4 __attribute__((ext_vector_type(4)));
typedef unsigned short u16;
typedef unsigned int u32;
typedef unsigned long long u64;

__device__ __forceinline__ u16 f2bf(float f) {
    union { bf16_t h; u16 u; } v; v.h = (bf16_t)f; return v.u;
}
__device__ __forceinline__ float bf2f(u16 b) {
    union { u16 u; bf16_t h; } v; v.u = b; return (float)v.h;
}
// swizzled u16 index into a stride-32 row-major [98][32] tile: 16-B chunk c of
// row r lives at chunk (c ^ (r&3)). Same formula on store and load.
__device__ __forceinline__ int qk_idx(int row, int d) {
    return row * QSTR + ((((d >> 3) ^ (row & 3)) << 3) | (d & 7));
}

// ---------------- K0: prep ----------------------------------------------------
// [0,49152)            qkv_w -> bf16
// [49152,65536)        proj_w -> bf16
// [65536,3276800)      mbT[w][h][i][l16][njp] = bf16(mask[w][i][j] + bias[rel_idx[i][j]][h])
//                      j = njp*16 + l16, njp in [0,8); PAD entries = -1e30
//                      (njp==7 or j>=98) -> softmax needs no masking branches
// [3276800,6488064)    x (f32) -> xbf (bf16), 8 elems/thread
__global__ void k0_prep(const float* __restrict__ qkv_w, const float* __restrict__ proj_w,
                        const float* __restrict__ mask,
                        const float* __restrict__ bias_table, const int* __restrict__ rel_idx,
                        const float* __restrict__ x,
                        u16* __restrict__ qkvw_bf, u16* __restrict__ pw_bf,
                        u16* __restrict__ mbT, u16* __restrict__ xbf)
{
    int t = blockIdx.x * 256 + threadIdx.x;
    if (t < 49152) {
        qkvw_bf[t] = f2bf(qkv_w[t]);
    } else if (t < 65536) {
        int r = t - 49152;
        pw_bf[r] = f2bf(proj_w[r]);
    } else if (t < 3276800) {
        int r = t - 65536;                  // [0, 64*4*98*128)
        int w    = r / 50176;               // 4*98*128
        int rem  = r - w * 50176;
        int hh   = rem / 12544;             // 98*128
        int rem2 = rem - hh * 12544;
        int i    = rem2 >> 7;
        int c    = rem2 & 127;
        int l16  = c >> 3;
        int njp  = c & 7;
        int j    = njp * 16 + l16;
        float val = -1e30f;                 // pad -> exp() underflows to 0
        if (njp < 7 && j < NTOK)
            val = mask[w * 9604 + i * NTOK + j] + bias_table[rel_idx[i * NTOK + j] * HEADS + hh];
        mbT[r] = f2bf(val);
    } else if (t < 6488064) {
        size_t idx = (size_t)(t - 3276800) * 8;   // 8 floats -> 8 bf16
        const float4 a0 = *reinterpret_cast<const float4*>(x + idx);
        const float4 a1 = *reinterpret_cast<const float4*>(x + idx + 4);
        u64 p0 = (u64)f2bf(a0.x) | ((u64)f2bf(a0.y) << 16) |
                 ((u64)f2bf(a0.z) << 32) | ((u64)f2bf(a0.w) << 48);
        u64 p1 = (u64)f2bf(a1.x) | ((u64)f2bf(a1.y) << 16) |
                 ((u64)f2bf(a1.z) << 32) | ((u64)f2bf(a1.w) << 48);
        *reinterpret_cast<u64*>(&xbf[idx])     = p0;
        *reinterpret_cast<u64*>(&xbf[idx + 4]) = p1;
    }
}

// ---------------- K1: qkv GEMM + attention, block = (window, head) -----------
// 256 threads (4 waves), LDS 32512 B -> 5 blocks/CU (20 waves/CU).
// Phase A: qkv GEMM for this head's 32 cols x 3 parts.
// Phase B: software-pipelined attention: wave w owns mt tiles {w, w+4};
//          tile2's QK MFMAs + mask loads issue between tile1's softmax and PV,
//          overlapping tile1's LDS round-trip latency.
__global__ __launch_bounds__(256, 5) void k_attn(
    const u16* __restrict__ xbf, const u16* __restrict__ qkvw_bf,
    const float* __restrict__ qkv_b, const u16* __restrict__ mbT,
    u16* __restrict__ OG)
{
    __shared__ __align__(16) u16 qL[NTOK * QSTR];     //  6272 B
    __shared__ __align__(16) u16 kL[NTOK * QSTR];     //  6272 B
    __shared__ __align__(16) u16 vL[HD * VSTR];       //  6656 B
    __shared__ __align__(16) u16 Pscr[4][16 * VSTR];  // 13312 B

    // XCD swizzle: keep the 4 head-blocks of a window on one XCD (x L2 reuse).
    // 8192 blocks = 8 XCDs * 1024 -> bijective. Window w lands on XCD w>>8.
    const int bh   = (blockIdx.x & 7) * 1024 + (blockIdx.x >> 3);
    const int b    = bh >> 2;
    const int h    = bh & 3;
    const int tid  = threadIdx.x;
    const int wave = tid >> 6;
    const int lane = tid & 63;
    const int l16  = lane & 15;
    const int quad = lane >> 4;

    const u16* xb = xbf + (size_t)b * (NTOK * DIM);

    // ---- phase A: qkv GEMM (21 part-major units over 4 waves) ---------------
    {
        const int u0 = (wave * 21) >> 2;        // 0,5,10,15
        const int u1 = ((wave + 1) * 21) >> 2;  // 5,10,15,21
        int cached = -1;
        bf16x8 Bf[2][4];
        float  cb[2];
        for (int u = u0; u < u1; ++u) {
            const int part = u / 7;
            const int mt   = u - part * 7;
            if (part != cached) {
                const u16* wp = qkvw_bf + (size_t)part * DIM * DIM;
#pragma unroll
                for (int nt2 = 0; nt2 < 2; ++nt2) {
                    const int col = h * HD + nt2 * 16 + l16;
#pragma unroll
                    for (int ks = 0; ks < 4; ++ks)
                        Bf[nt2][ks] = *reinterpret_cast<const bf16x8*>(
                            wp + col * DIM + quad * 8 + ks * 32);
                    cb[nt2] = qkv_b[part * DIM + col];
                }
                cached = part;
            }
            int arow = mt * 16 + l16;
            if (arow > 97) arow = 97;          // pad rows duplicate row 97 (discarded)
            bf16x8 af[4];
#pragma unroll
            for (int ks = 0; ks < 4; ++ks)
                af[ks] = *reinterpret_cast<const bf16x8*>(
                    xb + arow * DIM + quad * 8 + ks * 32);
            f32x4 acc0 = {0.f, 0.f, 0.f, 0.f};
            f32x4 acc1 = {0.f, 0.f, 0.f, 0.f};
            __builtin_amdgcn_s_setprio(1);
#pragma unroll
            for (int ks = 0; ks < 4; ++ks) {
                acc0 = __builtin_amdgcn_mfma_f32_16x16x32_bf16(af[ks], Bf[0][ks], acc0, 0, 0, 0);
                acc1 = __builtin_amdgcn_mfma_f32_16x16x32_bf16(af[ks], Bf[1][ks], acc1, 0, 0, 0);
            }
            __builtin_amdgcn_s_setprio(0);
            const int tokb = mt * 16 + quad * 4;
#pragma unroll
            for (int nt2 = 0; nt2 < 2; ++nt2) {
                const f32x4& acc = nt2 ? acc1 : acc0;
                const int d = nt2 * 16 + l16;          // 0..31 (head-local)
                const float cbv = cb[nt2];
                if (part == 0) {
#pragma unroll
                    for (int reg = 0; reg < 4; ++reg) {
                        int tok = tokb + reg;
                        if (tok < NTOK)
                            qL[qk_idx(tok, d)] = f2bf((acc[reg] + cbv) * SCALE);
                    }
                } else if (part == 1) {
#pragma unroll
                    for (int reg = 0; reg < 4; ++reg) {
                        int tok = tokb + reg;
                        if (tok < NTOK)
                            kL[qk_idx(tok, d)] = f2bf(acc[reg] + cbv);
                    }
                } else {
                    u16* vrow = &vL[d * VSTR];
                    if (tokb + 3 <= 97) {
                        u64 pack = 0;
#pragma unroll
                        for (int reg = 0; reg < 4; ++reg)
                            pack |= ((u64)f2bf(acc[reg] + cbv)) << (16 * reg);
                        *reinterpret_cast<u64*>(&vrow[tokb]) = pack;
                    } else if (tokb <= 97) {   // tokb == 96: tokens 96,97
                        u32 pack = (u32)f2bf(acc[0] + cbv) | ((u32)f2bf(acc[1] + cbv) << 16);
                        *reinterpret_cast<u32*>(&vrow[tokb]) = pack;
                    }
                }
            }
        }
    }
    __syncthreads();

    // ---- phase B: pipelined attention ---------------------------------------
    // Branchless softmax (mbT pads are -1e30 -> exp()=0); P stored UNNORMALIZED,
    // row-inverse applied at the O-write. K/Q LDS rows clamped to 97 (clamped
    // duplicates get -1e30 from mbT pads -> exp()=0 -> never contaminate).
    {
        const u16* mbtp = mbT + ((size_t)((b & (NW - 1)) * HEADS + h)) * (NTOK * 128);
        u16* ps = &Pscr[wave][0];
        const int qko = ((quad ^ (l16 & 3)) << 3);   // swizzled chunk offset for qL/kL reads

        bf16x8 kf[7];
#pragma unroll
        for (int nj = 0; nj < 7; ++nj) {
            int krow = nj * 16 + l16;
            if (krow > 97) krow = 97;          // clamp: avoid OOB-garbage K rows
            kf[nj] = *reinterpret_cast<const bf16x8*>(&kL[krow * QSTR + qko]);
        }

        // softmax: sacc+mrows -> unnormalized P in ps, rin = 1/rowsum
        auto softmax_tile = [&](const f32x4* sacc, const bf16x8* mrows, float* rin) {
#pragma unroll
            for (int reg = 0; reg < 4; ++reg) {
                float s[7];
#pragma unroll
                for (int nj = 0; nj < 7; ++nj)
                    s[nj] = sacc[nj][reg] + (float)mrows[reg][nj];
                float mx = fmaxf(fmaxf(fmaxf(s[0], s[1]), fmaxf(s[2], s[3])),
                                 fmaxf(fmaxf(s[4], s[5]), s[6]));
#pragma unroll
                for (int off = 1; off < 16; off <<= 1) mx = fmaxf(mx, __shfl_xor(mx, off));
                float p[7];
                float lsum = 0.f;
#pragma unroll
                for (int nj = 0; nj < 7; ++nj) {
                    p[nj] = __expf(s[nj] - mx);
                    lsum += p[nj];
                }
                u16* psr = &ps[(quad * 4 + reg) * VSTR];
#pragma unroll
                for (int nj = 0; nj < 6; ++nj)
                    psr[nj * 16 + l16] = f2bf(p[nj]);
                if (l16 < 8) psr[96 + l16] = f2bf(p[6]);   // j=96..103 (98+ unused)
#pragma unroll
                for (int off = 1; off < 16; off <<= 1) lsum += __shfl_xor(lsum, off);
                rin[reg] = 1.f / lsum;
            }
        };

        // PV from ps + vL, write O rows of tile mt
        auto pv_store = [&](int mt, const float* rin) {
            bf16x8 pf[3];
#pragma unroll
            for (int ks = 0; ks < 3; ++ks)
                pf[ks] = *reinterpret_cast<const bf16x8*>(&ps[l16 * VSTR + quad * 8 + ks * 32]);
#pragma unroll
            for (int nt = 0; nt < 2; ++nt) {
                f32x4 oacc = {0.f, 0.f, 0.f, 0.f};
                __builtin_amdgcn_s_setprio(1);
#pragma unroll
                for (int ks = 0; ks < 3; ++ks) {
                    bf16x8 vf = *reinterpret_cast<const bf16x8*>(
                        &vL[(nt * 16 + l16) * VSTR + quad * 8 + ks * 32]);
                    oacc = __builtin_amdgcn_mfma_f32_16x16x32_bf16(pf[ks], vf, oacc, 0, 0, 0);
                }
                __builtin_amdgcn_s_setprio(0);
                int d = nt * 16 + l16;
                float v96 = bf2f(vL[d * VSTR + 96]);
                float v97 = bf2f(vL[d * VSTR + 97]);
#pragma unroll
                for (int reg = 0; reg < 4; ++reg) {
                    int i = mt * 16 + quad * 4 + reg;
                    if (i < NTOK) {
                        float p96 = bf2f(ps[(quad * 4 + reg) * VSTR + 96]);
                        float p97 = bf2f(ps[(quad * 4 + reg) * VSTR + 97]);
                        OG[((size_t)b * NTOK + i) * DIM + h * HD + d] =
                            f2bf((oacc[reg] + p96 * v96 + p97 * v97) * rin[reg]);
                    }
                }
            }
        };

        const int mt1 = wave;          // 0..3: rows <= 63, no clamps needed
        const int mt2 = wave + 4;      // 4..7; 7 -> inactive (wave 3)
        const bool has2 = (mt2 < 7);

        // tile1: mask loads + QK
        bf16x8 mrows1[4];
#pragma unroll
        for (int reg = 0; reg < 4; ++reg) {
            int i = mt1 * 16 + quad * 4 + reg;                  // <= 63
            mrows1[reg] = *reinterpret_cast<const bf16x8*>(&mbtp[i * 128 + l16 * 8]);
        }
        bf16x8 qf1 = *reinterpret_cast<const bf16x8*>(&qL[(mt1 * 16 + l16) * QSTR + qko]);
        f32x4 sacc1[7];
        __builtin_amdgcn_s_setprio(1);
#pragma unroll
        for (int nj = 0; nj < 7; ++nj) {
            f32x4 z = {0.f, 0.f, 0.f, 0.f};
            sacc1[nj] = __builtin_amdgcn_mfma_f32_16x16x32_bf16(qf1, kf[nj], z, 0, 0, 0);
        }
        __builtin_amdgcn_s_setprio(0);

        float rin1[4];
        softmax_tile(sacc1, mrows1, rin1);

        // tile2: QK + mask loads issued under tile1's PV latency
        f32x4 sacc2[7];
        bf16x8 mrows2[4];
        if (has2) {
            int qrow2 = mt2 * 16 + l16;
            if (qrow2 > 97) qrow2 = 97;        // clamp: duplicate rows, outputs discarded
            bf16x8 qf2 = *reinterpret_cast<const bf16x8*>(&qL[qrow2 * QSTR + qko]);
            __builtin_amdgcn_s_setprio(1);
#pragma unroll
            for (int nj = 0; nj < 7; ++nj) {
                f32x4 z = {0.f, 0.f, 0.f, 0.f};
                sacc2[nj] = __builtin_amdgcn_mfma_f32_16x16x32_bf16(qf2, kf[nj], z, 0, 0, 0);
            }
            __builtin_amdgcn_s_setprio(0);
#pragma unroll
            for (int reg = 0; reg < 4; ++reg) {
                int i  = mt2 * 16 + quad * 4 + reg;
                int ic = (i > 97) ? 97 : i;
                mrows2[reg] = *reinterpret_cast<const bf16x8*>(&mbtp[ic * 128 + l16 * 8]);
            }
        }

        pv_store(mt1, rin1);                   // reads ps BEFORE softmax2 rewrites it
                                               // (same-wave DS ops are in-order)
        if (has2) {
            float rin2[4];
            softmax_tile(sacc2, mrows2, rin2);
            pv_store(mt2, rin2);
        }
    }
}

// ---------------- K2: proj GEMM, block = window, LDS-staged A ----------------
// A (OG tile, 25 KB) staged once cooperatively; waves then read LDS instead of
// 4x-redundant global loads. LDS 26656 B -> 6 blocks/CU.
// XCD swizzle matches k_attn's writer mapping (window w -> XCD w>>8).
__global__ __launch_bounds__(256, 6) void k_proj(
    const u16* __restrict__ OG, const u16* __restrict__ pw_bf,
    const float* __restrict__ proj_b, float* __restrict__ out)
{
    __shared__ __align__(16) u16 A[98 * 136];   // stride 136: 2-way banks (free)

    const int b    = ((blockIdx.x & 7) << 8) + (blockIdx.x >> 3);   // 2048 = 8*256, bijective
    const int tid  = threadIdx.x;
    const int wave = tid >> 6;
    const int lane = tid & 63;
    const int l16  = lane & 15;
    const int quad = lane >> 4;

    bf16x8 bw[2][4];
    float  pb[2];
#pragma unroll
    for (int nt2 = 0; nt2 < 2; ++nt2) {
        const int col = (wave * 2 + nt2) * 16 + l16;
#pragma unroll
        for (int ks = 0; ks < 4; ++ks)
            bw[nt2][ks] = *reinterpret_cast<const bf16x8*>(
                pw_bf + col * DIM + quad * 8 + ks * 32);
        pb[nt2] = proj_b[col];
    }

    const u16* ob = OG + (size_t)b * (NTOK * DIM);
    for (int idx = tid; idx < (NTOK * DIM / 8); idx += 256) {   // 1568 b128 loads
        int row = idx >> 4;
        int c8  = idx & 15;
        *reinterpret_cast<bf16x8*>(&A[row * 136 + c8 * 8]) =
            *reinterpret_cast<const bf16x8*>(ob + row * DIM + c8 * 8);
    }
    __syncthreads();

    for (int mt = 0; mt < 7; ++mt) {
        int arow = mt * 16 + l16;
        if (arow > 97) arow = 97;
        bf16x8 af[4];
#pragma unroll
        for (int ks = 0; ks < 4; ++ks)
            af[ks] = *reinterpret_cast<const bf16x8*>(&A[arow * 136 + quad * 8 + ks * 32]);
        f32x4 acc0 = {0.f, 0.f, 0.f, 0.f};
        f32x4 acc1 = {0.f, 0.f, 0.f, 0.f};
#pragma unroll
        for (int ks = 0; ks < 4; ++ks) {
            acc0 = __builtin_amdgcn_mfma_f32_16x16x32_bf16(af[ks], bw[0][ks], acc0, 0, 0, 0);
            acc1 = __builtin_amdgcn_mfma_f32_16x16x32_bf16(af[ks], bw[1][ks], acc1, 0, 0, 0);
        }
#pragma unroll
        for (int nt2 = 0; nt2 < 2; ++nt2) {
            const f32x4& acc = nt2 ? acc1 : acc0;
            const int col = (wave * 2 + nt2) * 16 + l16;
#pragma unroll
            for (int reg = 0; reg < 4; ++reg) {
                int row = mt * 16 + quad * 4 + reg;
                if (row < NTOK)
                    out[((size_t)b * NTOK + row) * DIM + col] = acc[reg] + pb[nt2];
            }
        }
    }
}

// ---------------- launch ------------------------------------------------------
extern "C" void kernel_launch(void* const* d_in, const int* in_sizes, int n_in,
                              void* d_out, int out_size, void* d_ws, size_t ws_size,
                              hipStream_t stream)
{
    const float* x       = (const float*)d_in[0];
    const float* mask    = (const float*)d_in[1];
    const float* qkv_w   = (const float*)d_in[2];
    const float* qkv_b   = (const float*)d_in[3];
    const float* proj_w  = (const float*)d_in[4];
    const float* proj_b  = (const float*)d_in[5];
    const float* bias_tb = (const float*)d_in[6];
    const int*   rel_idx = (const int*)d_in[7];
    float* out = (float*)d_out;

    char* ws = (char*)d_ws;
    u16* qkvw_bf = (u16*)(ws + 0);          //    98304 B
    u16* pw_bf   = (u16*)(ws + 98304);      //    32768 B
    u16* mbT     = (u16*)(ws + 131072);     //  6422528 B (64*4*98*128 u16)
    u16* xbf     = (u16*)(ws + 6553600);    // 51380224 B (2048*98*128 u16)
    u16* OG      = (u16*)(ws + 57933824);   // 51380224 B (2048*98*128 u16)
    // total ~109.3 MB

    k0_prep<<<25344, 256, 0, stream>>>(qkv_w, proj_w, mask, bias_tb, rel_idx, x,
                                       qkvw_bf, pw_bf, mbT, xbf);
    k_attn<<<BWIN * HEADS, 256, 0, stream>>>(xbf, qkvw_bf, qkv_b, mbT, OG);
    k_proj<<<BWIN, 256, 0, stream>>>(OG, pw_bf, proj_b, out);
}

// Round 9
// 352.339 us; speedup vs baseline: 1.7354x; 1.0107x over previous
//
#include <hip/hip_runtime.h>
#include <stdint.h>

#define NTOK 98
#define DIM 128
#define HEADS 4
#define HD 32
#define BWIN 2048
#define NW 64
#define SCALE 0.17677669529663687f
#define LOG2E 1.4426950408889634f
#define QSTR 32    // qL/kL row stride in u16 (64 B) + XOR chunk swizzle (16-B granules)
#define VSTR 104   // vL / Pscr row stride in u16: 208 B -> 16B-aligned, 2-way banks (free)

typedef __bf16 bf16_t;
typedef bf16_t bf16x8 __attribute__((ext_vector_type(8)));
typedef float f32x4 __attribute__((ext_vector_type(4)));
typedef unsigned short u16;
typedef unsigned int u32;
typedef unsigned long long u64;

__device__ __forceinline__ u16 f2bf(float f) {
    union { bf16_t h; u16 u; } v; v.h = (bf16_t)f; return v.u;
}
__device__ __forceinline__ float bf2f(u16 b) {
    union { u16 u; bf16_t h; } v; v.u = b; return (float)v.h;
}
// swizzled u16 index into a stride-32 row-major [98][32] tile: 16-B chunk c of
// row r lives at chunk (c ^ (r&3)). Same formula on store and load.
__device__ __forceinline__ int qk_idx(int row, int d) {
    return row * QSTR + ((((d >> 3) ^ (row & 3)) << 3) | (d & 7));
}

// ---------------- K0: prep ----------------------------------------------------
// [0,49152)            qkv_w -> bf16
// [49152,65536)        proj_w -> bf16
// [65536,3276800)      mbT[w][h][i][l16][njp] = bf16(LOG2E*(mask[w][i][j] + bias[..][h]))
//                      j = njp*16 + l16, njp in [0,8); PAD entries = -1e30
//                      -> softmax runs in exp2 domain, branchless
// [3276800,6488064)    x (f32) -> xbf (bf16), 8 elems/thread
__global__ void k0_prep(const float* __restrict__ qkv_w, const float* __restrict__ proj_w,
                        const float* __restrict__ mask,
                        const float* __restrict__ bias_table, const int* __restrict__ rel_idx,
                        const float* __restrict__ x,
                        u16* __restrict__ qkvw_bf, u16* __restrict__ pw_bf,
                        u16* __restrict__ mbT, u16* __restrict__ xbf)
{
    int t = blockIdx.x * 256 + threadIdx.x;
    if (t < 49152) {
        qkvw_bf[t] = f2bf(qkv_w[t]);
    } else if (t < 65536) {
        int r = t - 49152;
        pw_bf[r] = f2bf(proj_w[r]);
    } else if (t < 3276800) {
        int r = t - 65536;                  // [0, 64*4*98*128)
        int w    = r / 50176;               // 4*98*128
        int rem  = r - w * 50176;
        int hh   = rem / 12544;             // 98*128
        int rem2 = rem - hh * 12544;
        int i    = rem2 >> 7;
        int c    = rem2 & 127;
        int l16  = c >> 3;
        int njp  = c & 7;
        int j    = njp * 16 + l16;
        float val = -1e30f;                 // pad -> exp2() = 0
        if (njp < 7 && j < NTOK)
            val = LOG2E * (mask[w * 9604 + i * NTOK + j]
                           + bias_table[rel_idx[i * NTOK + j] * HEADS + hh]);
        mbT[r] = f2bf(val);
    } else if (t < 6488064) {
        size_t idx = (size_t)(t - 3276800) * 8;   // 8 floats -> 8 bf16
        const float4 a0 = *reinterpret_cast<const float4*>(x + idx);
        const float4 a1 = *reinterpret_cast<const float4*>(x + idx + 4);
        u64 p0 = (u64)f2bf(a0.x) | ((u64)f2bf(a0.y) << 16) |
                 ((u64)f2bf(a0.z) << 32) | ((u64)f2bf(a0.w) << 48);
        u64 p1 = (u64)f2bf(a1.x) | ((u64)f2bf(a1.y) << 16) |
                 ((u64)f2bf(a1.z) << 32) | ((u64)f2bf(a1.w) << 48);
        *reinterpret_cast<u64*>(&xbf[idx])     = p0;
        *reinterpret_cast<u64*>(&xbf[idx + 4]) = p1;
    }
}

// ---------------- K1: qkv GEMM + attention, block = (window, head) -----------
// 256 threads (4 waves), LDS 32512 B -> 5 blocks/CU (20 waves/CU).
// Phase A: qkv GEMM for this head's 32 cols x 3 parts; q pre-scaled to exp2
//          domain (SCALE*LOG2E).
// Phase B: pipelined attention, no-max exp2 softmax (scores provably bounded;
//          mbT pads -1e30 -> exp2=0). tile2's QK is pinned between softmax1
//          and PV1 via sched_barrier(0) so the compiler can't sink it.
// O -> global bf16 OG[(b*4+h)][i][d] (head-major: block-private cachelines).
__global__ __launch_bounds__(256, 5) void k_attn(
    const u16* __restrict__ xbf, const u16* __restrict__ qkvw_bf,
    const float* __restrict__ qkv_b, const u16* __restrict__ mbT,
    u16* __restrict__ OG)
{
    __shared__ __align__(16) u16 qL[NTOK * QSTR];     //  6272 B
    __shared__ __align__(16) u16 kL[NTOK * QSTR];     //  6272 B
    __shared__ __align__(16) u16 vL[HD * VSTR];       //  6656 B
    __shared__ __align__(16) u16 Pscr[4][16 * VSTR];  // 13312 B

    // XCD swizzle: keep the 4 head-blocks of a window on one XCD (x L2 reuse).
    // 8192 blocks = 8 XCDs * 1024 -> bijective.
    const int bh   = (blockIdx.x & 7) * 1024 + (blockIdx.x >> 3);
    const int b    = bh >> 2;
    const int h    = bh & 3;
    const int tid  = threadIdx.x;
    const int wave = tid >> 6;
    const int lane = tid & 63;
    const int l16  = lane & 15;
    const int quad = lane >> 4;

    const u16* xb = xbf + (size_t)b * (NTOK * DIM);

    // ---- phase A: qkv GEMM (21 part-major units over 4 waves) ---------------
    {
        const int u0 = (wave * 21) >> 2;        // 0,5,10,15
        const int u1 = ((wave + 1) * 21) >> 2;  // 5,10,15,21
        int cached = -1;
        bf16x8 Bf[2][4];
        float  cb[2];
        for (int u = u0; u < u1; ++u) {
            const int part = u / 7;
            const int mt   = u - part * 7;
            if (part != cached) {
                const u16* wp = qkvw_bf + (size_t)part * DIM * DIM;
#pragma unroll
                for (int nt2 = 0; nt2 < 2; ++nt2) {
                    const int col = h * HD + nt2 * 16 + l16;
#pragma unroll
                    for (int ks = 0; ks < 4; ++ks)
                        Bf[nt2][ks] = *reinterpret_cast<const bf16x8*>(
                            wp + col * DIM + quad * 8 + ks * 32);
                    cb[nt2] = qkv_b[part * DIM + col];
                }
                cached = part;
            }
            int arow = mt * 16 + l16;
            if (arow > 97) arow = 97;          // pad rows duplicate row 97 (discarded)
            bf16x8 af[4];
#pragma unroll
            for (int ks = 0; ks < 4; ++ks)
                af[ks] = *reinterpret_cast<const bf16x8*>(
                    xb + arow * DIM + quad * 8 + ks * 32);
            f32x4 acc0 = {0.f, 0.f, 0.f, 0.f};
            f32x4 acc1 = {0.f, 0.f, 0.f, 0.f};
            __builtin_amdgcn_s_setprio(1);
#pragma unroll
            for (int ks = 0; ks < 4; ++ks) {
                acc0 = __builtin_amdgcn_mfma_f32_16x16x32_bf16(af[ks], Bf[0][ks], acc0, 0, 0, 0);
                acc1 = __builtin_amdgcn_mfma_f32_16x16x32_bf16(af[ks], Bf[1][ks], acc1, 0, 0, 0);
            }
            __builtin_amdgcn_s_setprio(0);
            const int tokb = mt * 16 + quad * 4;
#pragma unroll
            for (int nt2 = 0; nt2 < 2; ++nt2) {
                const f32x4& acc = nt2 ? acc1 : acc0;
                const int d = nt2 * 16 + l16;          // 0..31 (head-local)
                const float cbv = cb[nt2];
                if (part == 0) {
#pragma unroll
                    for (int reg = 0; reg < 4; ++reg) {
                        int tok = tokb + reg;
                        if (tok < NTOK)
                            qL[qk_idx(tok, d)] = f2bf((acc[reg] + cbv) * (SCALE * LOG2E));
                    }
                } else if (part == 1) {
#pragma unroll
                    for (int reg = 0; reg < 4; ++reg) {
                        int tok = tokb + reg;
                        if (tok < NTOK)
                            kL[qk_idx(tok, d)] = f2bf(acc[reg] + cbv);
                    }
                } else {
                    u16* vrow = &vL[d * VSTR];
                    if (tokb + 3 <= 97) {
                        u64 pack = 0;
#pragma unroll
                        for (int reg = 0; reg < 4; ++reg)
                            pack |= ((u64)f2bf(acc[reg] + cbv)) << (16 * reg);
                        *reinterpret_cast<u64*>(&vrow[tokb]) = pack;
                    } else if (tokb <= 97) {   // tokb == 96: tokens 96,97
                        u32 pack = (u32)f2bf(acc[0] + cbv) | ((u32)f2bf(acc[1] + cbv) << 16);
                        *reinterpret_cast<u32*>(&vrow[tokb]) = pack;
                    }
                }
            }
        }
    }
    __syncthreads();

    // ---- phase B: pipelined attention ---------------------------------------
    // No-max exp2 softmax: p = exp2(sacc + mb). Scores bounded (|s| << 80) so
    // no overflow; pads are -1e30 -> exp2=0. P stored UNNORMALIZED; row-inverse
    // applied at the O-write. K/Q LDS rows clamped to 97 (clamped duplicates
    // get -1e30 pads -> 0 -> never contaminate sums).
    {
        const u16* mbtp = mbT + ((size_t)((b & (NW - 1)) * HEADS + h)) * (NTOK * 128);
        u16* ps = &Pscr[wave][0];
        const int qko = ((quad ^ (l16 & 3)) << 3);   // swizzled chunk offset for qL/kL reads

        bf16x8 kf[7];
#pragma unroll
        for (int nj = 0; nj < 7; ++nj) {
            int krow = nj * 16 + l16;
            if (krow > 97) krow = 97;          // clamp: avoid OOB-garbage K rows
            kf[nj] = *reinterpret_cast<const bf16x8*>(&kL[krow * QSTR + qko]);
        }

        // softmax: unnormalized P = exp2(s) into ps; rin = 1/rowsum
        auto softmax_tile = [&](const f32x4* sacc, const bf16x8* mrows, float* rin) {
#pragma unroll
            for (int reg = 0; reg < 4; ++reg) {
                float p[7];
#pragma unroll
                for (int nj = 0; nj < 7; ++nj)
                    p[nj] = __builtin_amdgcn_exp2f(sacc[nj][reg] + (float)mrows[reg][nj]);
                u16* psr = &ps[(quad * 4 + reg) * VSTR];
#pragma unroll
                for (int nj = 0; nj < 6; ++nj)
                    psr[nj * 16 + l16] = f2bf(p[nj]);
                if (l16 < 8) psr[96 + l16] = f2bf(p[6]);   // j=96..103 (98+ unused)
                float lsum = ((p[0] + p[1]) + (p[2] + p[3])) + ((p[4] + p[5]) + p[6]);
#pragma unroll
                for (int off = 1; off < 16; off <<= 1) lsum += __shfl_xor(lsum, off);
                rin[reg] = __builtin_amdgcn_rcpf(lsum);
            }
        };

        // PV from ps + vL, write O rows of tile mt (head-major OG)
        auto pv_store = [&](int mt, const float* rin) {
            bf16x8 pf[3];
#pragma unroll
            for (int ks = 0; ks < 3; ++ks)
                pf[ks] = *reinterpret_cast<const bf16x8*>(&ps[l16 * VSTR + quad * 8 + ks * 32]);
#pragma unroll
            for (int nt = 0; nt < 2; ++nt) {
                f32x4 oacc = {0.f, 0.f, 0.f, 0.f};
                __builtin_amdgcn_s_setprio(1);
#pragma unroll
                for (int ks = 0; ks < 3; ++ks) {
                    bf16x8 vf = *reinterpret_cast<const bf16x8*>(
                        &vL[(nt * 16 + l16) * VSTR + quad * 8 + ks * 32]);
                    oacc = __builtin_amdgcn_mfma_f32_16x16x32_bf16(pf[ks], vf, oacc, 0, 0, 0);
                }
                __builtin_amdgcn_s_setprio(0);
                int d = nt * 16 + l16;
                float v96 = bf2f(vL[d * VSTR + 96]);
                float v97 = bf2f(vL[d * VSTR + 97]);
#pragma unroll
                for (int reg = 0; reg < 4; ++reg) {
                    int i = mt * 16 + quad * 4 + reg;
                    if (i < NTOK) {
                        float p96 = bf2f(ps[(quad * 4 + reg) * VSTR + 96]);
                        float p97 = bf2f(ps[(quad * 4 + reg) * VSTR + 97]);
                        OG[((size_t)bh * NTOK + i) * HD + d] =
                            f2bf((oacc[reg] + p96 * v96 + p97 * v97) * rin[reg]);
                    }
                }
            }
        };

        const int mt1 = wave;          // 0..3: rows <= 63, no clamps needed
        const int mt2 = wave + 4;      // 4..7; 7 -> inactive (wave 3)
        const bool has2 = (mt2 < 7);

        // tile1: mask loads + QK
        bf16x8 mrows1[4];
#pragma unroll
        for (int reg = 0; reg < 4; ++reg) {
            int i = mt1 * 16 + quad * 4 + reg;                  // <= 63
            mrows1[reg] = *reinterpret_cast<const bf16x8*>(&mbtp[i * 128 + l16 * 8]);
        }
        bf16x8 qf1 = *reinterpret_cast<const bf16x8*>(&qL[(mt1 * 16 + l16) * QSTR + qko]);
        f32x4 sacc1[7];
        __builtin_amdgcn_s_setprio(1);
#pragma unroll
        for (int nj = 0; nj < 7; ++nj) {
            f32x4 z = {0.f, 0.f, 0.f, 0.f};
            sacc1[nj] = __builtin_amdgcn_mfma_f32_16x16x32_bf16(qf1, kf[nj], z, 0, 0, 0);
        }
        __builtin_amdgcn_s_setprio(0);

        float rin1[4];
        softmax_tile(sacc1, mrows1, rin1);

        // tile2: QK + mask loads PINNED between softmax1 and PV1 so the
        // scheduler cannot sink the MFMAs below pv_store (round-7 lesson:
        // without the fence it did, and the pipeline never existed).
        f32x4 sacc2[7];
        bf16x8 mrows2[4];
        if (has2) {
            __builtin_amdgcn_sched_barrier(0);
            int qrow2 = mt2 * 16 + l16;
            if (qrow2 > 97) qrow2 = 97;        // clamp: duplicate rows, outputs discarded
            bf16x8 qf2 = *reinterpret_cast<const bf16x8*>(&qL[qrow2 * QSTR + qko]);
            __builtin_amdgcn_s_setprio(1);
#pragma unroll
            for (int nj = 0; nj < 7; ++nj) {
                f32x4 z = {0.f, 0.f, 0.f, 0.f};
                sacc2[nj] = __builtin_amdgcn_mfma_f32_16x16x32_bf16(qf2, kf[nj], z, 0, 0, 0);
            }
            __builtin_amdgcn_s_setprio(0);
#pragma unroll
            for (int reg = 0; reg < 4; ++reg) {
                int i  = mt2 * 16 + quad * 4 + reg;
                int ic = (i > 97) ? 97 : i;
                mrows2[reg] = *reinterpret_cast<const bf16x8*>(&mbtp[ic * 128 + l16 * 8]);
            }
            __builtin_amdgcn_sched_barrier(0);
        }

        pv_store(mt1, rin1);                   // reads ps BEFORE softmax2 rewrites it
                                               // (same-wave DS ops are in-order)
        if (has2) {
            float rin2[4];
            softmax_tile(sacc2, mrows2, rin2);
            pv_store(mt2, rin2);
        }
    }
}

// ---------------- K2: proj GEMM, block = window, LDS-staged A ----------------
// A staged once from head-major OG; waves read LDS. LDS 26656 B -> 6 blocks/CU.
// XCD swizzle matches k_attn's writer mapping (window w -> XCD w>>8).
__global__ __launch_bounds__(256, 6) void k_proj(
    const u16* __restrict__ OG, const u16* __restrict__ pw_bf,
    const float* __restrict__ proj_b, float* __restrict__ out)
{
    __shared__ __align__(16) u16 A[98 * 136];   // stride 136: 2-way banks (free)

    const int b    = ((blockIdx.x & 7) << 8) + (blockIdx.x >> 3);   // 2048 = 8*256, bijective
    const int tid  = threadIdx.x;
    const int wave = tid >> 6;
    const int lane = tid & 63;
    const int l16  = lane & 15;
    const int quad = lane >> 4;

    bf16x8 bw[2][4];
    float  pb[2];
#pragma unroll
    for (int nt2 = 0; nt2 < 2; ++nt2) {
        const int col = (wave * 2 + nt2) * 16 + l16;
#pragma unroll
        for (int ks = 0; ks < 4; ++ks)
            bw[nt2][ks] = *reinterpret_cast<const bf16x8*>(
                pw_bf + col * DIM + quad * 8 + ks * 32);
        pb[nt2] = proj_b[col];
    }

    // stage head-major OG[(b*4+h)][row][d] -> A[row][h*32+d]
    const u16* ob = OG + (size_t)b * (HEADS * NTOK * HD);
    for (int idx = tid; idx < (NTOK * DIM / 8); idx += 256) {   // 1568 b128 loads
        int row = idx >> 4;
        int c8  = idx & 15;          // 16-byte chunk within the 128-col row
        int hh  = c8 >> 2;
        int d8  = c8 & 3;
        *reinterpret_cast<bf16x8*>(&A[row * 136 + c8 * 8]) =
            *reinterpret_cast<const bf16x8*>(ob + ((size_t)hh * NTOK + row) * HD + d8 * 8);
    }
    __syncthreads();

    for (int mt = 0; mt < 7; ++mt) {
        int arow = mt * 16 + l16;
        if (arow > 97) arow = 97;
        bf16x8 af[4];
#pragma unroll
        for (int ks = 0; ks < 4; ++ks)
            af[ks] = *reinterpret_cast<const bf16x8*>(&A[arow * 136 + quad * 8 + ks * 32]);
        f32x4 acc0 = {0.f, 0.f, 0.f, 0.f};
        f32x4 acc1 = {0.f, 0.f, 0.f, 0.f};
#pragma unroll
        for (int ks = 0; ks < 4; ++ks) {
            acc0 = __builtin_amdgcn_mfma_f32_16x16x32_bf16(af[ks], bw[0][ks], acc0, 0, 0, 0);
            acc1 = __builtin_amdgcn_mfma_f32_16x16x32_bf16(af[ks], bw[1][ks], acc1, 0, 0, 0);
        }
#pragma unroll
        for (int nt2 = 0; nt2 < 2; ++nt2) {
            const f32x4& acc = nt2 ? acc1 : acc0;
            const int col = (wave * 2 + nt2) * 16 + l16;
#pragma unroll
            for (int reg = 0; reg < 4; ++reg) {
                int row = mt * 16 + quad * 4 + reg;
                if (row < NTOK)
                    out[((size_t)b * NTOK + row) * DIM + col] = acc[reg] + pb[nt2];
            }
        }
    }
}

// ---------------- launch ------------------------------------------------------
extern "C" void kernel_launch(void* const* d_in, const int* in_sizes, int n_in,
                              void* d_out, int out_size, void* d_ws, size_t ws_size,
                              hipStream_t stream)
{
    const float* x       = (const float*)d_in[0];
    const float* mask    = (const float*)d_in[1];
    const float* qkv_w   = (const float*)d_in[2];
    const float* qkv_b   = (const float*)d_in[3];
    const float* proj_w  = (const float*)d_in[4];
    const float* proj_b  = (const float*)d_in[5];
    const float* bias_tb = (const float*)d_in[6];
    const int*   rel_idx = (const int*)d_in[7];
    float* out = (float*)d_out;

    char* ws = (char*)d_ws;
    u16* qkvw_bf = (u16*)(ws + 0);          //    98304 B
    u16* pw_bf   = (u16*)(ws + 98304);      //    32768 B
    u16* mbT     = (u16*)(ws + 131072);     //  6422528 B (64*4*98*128 u16)
    u16* xbf     = (u16*)(ws + 6553600);    // 51380224 B (2048*98*128 u16)
    u16* OG      = (u16*)(ws + 57933824);   // 51380224 B (2048*4*98*32 u16, head-major)
    // total ~109.3 MB

    k0_prep<<<25344, 256, 0, stream>>>(qkv_w, proj_w, mask, bias_tb, rel_idx, x,
                                       qkvw_bf, pw_bf, mbT, xbf);
    k_attn<<<BWIN * HEADS, 256, 0, stream>>>(xbf, qkvw_bf, qkv_b, mbT, OG);
    k_proj<<<BWIN, 256, 0, stream>>>(OG, pw_bf, proj_b, out);
}